// Round 1
// baseline (1005.689 us; speedup 1.0000x reference)
//
#include <hip/hip_runtime.h>

#define NN 100000
#define EE 1600000
#define FIN 128
#define HH 64

// ---------------- zero counts ----------------
__global__ __launch_bounds__(256) void zero2_kernel(int* __restrict__ a, int* __restrict__ b, int n) {
    int i = blockIdx.x * blockDim.x + threadIdx.x;
    if (i < n) { a[i] = 0; b[i] = 0; }
}

// ---------------- degree count ----------------
__global__ __launch_bounds__(256) void count_kernel(const int* __restrict__ col, int E, int* __restrict__ cnt) {
    int i = blockIdx.x * blockDim.x + threadIdx.x;
    if (i < E) atomicAdd(&cnt[col[i]], 1);
}

// ---------------- exclusive scan (3-kernel) ----------------
// scan1: each block handles 1024 elements (256 thr x 4), writes within-block
// exclusive scan to off[] and block total to bsum[b].
__global__ __launch_bounds__(256) void scan1_kernel(const int* __restrict__ cnt, int n,
                                                    int* __restrict__ off, int* __restrict__ bsum) {
    __shared__ int sdata[256];
    int t = threadIdx.x;
    int base = blockIdx.x * 1024 + t * 4;
    int v0 = (base + 0 < n) ? cnt[base + 0] : 0;
    int v1 = (base + 1 < n) ? cnt[base + 1] : 0;
    int v2 = (base + 2 < n) ? cnt[base + 2] : 0;
    int v3 = (base + 3 < n) ? cnt[base + 3] : 0;
    int s = v0 + v1 + v2 + v3;
    sdata[t] = s;
    __syncthreads();
    for (int d = 1; d < 256; d <<= 1) {
        int add = (t >= d) ? sdata[t - d] : 0;
        __syncthreads();
        sdata[t] += add;
        __syncthreads();
    }
    int incl = sdata[t];
    int ex = incl - s;
    if (base + 0 < n) off[base + 0] = ex;
    if (base + 1 < n) off[base + 1] = ex + v0;
    if (base + 2 < n) off[base + 2] = ex + v0 + v1;
    if (base + 3 < n) off[base + 3] = ex + v0 + v1 + v2;
    if (t == 255) bsum[blockIdx.x] = incl;
}

// scan2: single block, exclusive scan of nb block sums in place (nb <= 128)
__global__ __launch_bounds__(128) void scan2_kernel(int* __restrict__ bsum, int nb) {
    __shared__ int sdata[128];
    int t = threadIdx.x;
    int v = (t < nb) ? bsum[t] : 0;
    sdata[t] = v;
    __syncthreads();
    for (int d = 1; d < 128; d <<= 1) {
        int add = (t >= d) ? sdata[t - d] : 0;
        __syncthreads();
        sdata[t] += add;
        __syncthreads();
    }
    if (t < nb) bsum[t] = sdata[t] - v;  // exclusive
}

// scan3: add block offsets, also init cursor = off
__global__ __launch_bounds__(256) void scan3_kernel(int* __restrict__ off, const int* __restrict__ bsum,
                                                    int n, int* __restrict__ cursor) {
    int i = blockIdx.x * blockDim.x + threadIdx.x;
    if (i < n) {
        int o = off[i] + bsum[i >> 10];
        off[i] = o;
        cursor[i] = o;
    }
}

// ---------------- CSR fill ----------------
__global__ __launch_bounds__(256) void fill_kernel(const int* __restrict__ row, const int* __restrict__ col,
                                                   int E, int* __restrict__ cursor, int* __restrict__ csr) {
    int i = blockIdx.x * blockDim.x + threadIdx.x;
    if (i < E) {
        int c = col[i];
        int p = atomicAdd(&cursor[c], 1);
        csr[p] = row[i];
    }
}

// ---------------- dinv (3 configs) ----------------
__global__ __launch_bounds__(256) void dinv_kernel(const int* __restrict__ cp, const int* __restrict__ cs,
                                                   float* __restrict__ dp1, float* __restrict__ dp2,
                                                   float* __restrict__ ds2, int n) {
    int i = blockIdx.x * blockDim.x + threadIdx.x;
    if (i < n) {
        float fp = (float)cp[i];
        float fs = (float)cs[i];
        dp1[i] = rsqrtf(fp + 0.3f);
        dp2[i] = rsqrtf(fp + 0.5f);
        ds2[i] = rsqrtf(fs + 0.5f);
    }
}

// ---------------- fused dual GEMM: h1 = x@w1^T + b1, h2 = x@w2^T + b2 ----------------
// block = 256 (4 waves), each wave handles 8 rows; lane = output col (HH=64).
// W (both sets) staged in LDS as [set][kk][lane] float4 = 64KB.
__global__ __launch_bounds__(256, 2) void gemm_kernel(const float* __restrict__ x,
                                                      const float* __restrict__ w1, const float* __restrict__ b1,
                                                      const float* __restrict__ w2, const float* __restrict__ b2,
                                                      float* __restrict__ h1, float* __restrict__ h2) {
    __shared__ float4 Wp[2][32][64];  // 64 KB
    int t = threadIdx.x;
    const float4* w1v = (const float4*)w1;  // w[j][k]: j*32 + kk (float4 granules)
    const float4* w2v = (const float4*)w2;
    for (int f = t; f < 4096; f += 256) {
        int s  = f >> 11;
        int j  = (f >> 5) & 63;
        int kk = f & 31;
        Wp[s][kk][j] = (s == 0) ? w1v[j * 32 + kk] : w2v[j * 32 + kk];
    }
    __syncthreads();

    int lane = t & 63;
    int wave = t >> 6;
    int row0 = blockIdx.x * 32 + wave * 8;
    float bb1 = b1[lane], bb2 = b2[lane];
    float acc1[8], acc2[8];
#pragma unroll
    for (int i = 0; i < 8; i++) { acc1[i] = bb1; acc2[i] = bb2; }

    const float4* xv = (const float4*)x;  // x[row][k] -> xv[row*32 + kk]
    for (int kk = 0; kk < 32; kk++) {
        float4 wv1 = Wp[0][kk][lane];
        float4 wv2 = Wp[1][kk][lane];
#pragma unroll
        for (int i = 0; i < 8; i++) {
            float4 xq = xv[(row0 + i) * 32 + kk];
            acc1[i] += xq.x * wv1.x + xq.y * wv1.y + xq.z * wv1.z + xq.w * wv1.w;
            acc2[i] += xq.x * wv2.x + xq.y * wv2.y + xq.z * wv2.z + xq.w * wv2.w;
        }
    }
#pragma unroll
    for (int i = 0; i < 8; i++) {
        h1[(row0 + i) * 64 + lane] = acc1[i];
        h2[(row0 + i) * 64 + lane] = acc2[i];
    }
}

// ---------------- SpMM propagation pass (gather form, CSR by dst) ----------------
// y[c] = (1-eps)*h[c] + eps*dinv[c]^2*h[c] + sum_e dinv[src]*dinv[c]*h[src]  (+ extra[c])
// 16 threads per node, each owns 4 features (float4).
__global__ __launch_bounds__(256) void spmm_kernel(const float* __restrict__ hin,
                                                   const int* __restrict__ off,
                                                   const int* __restrict__ cnt,
                                                   const int* __restrict__ csr,
                                                   const float* __restrict__ dinv,
                                                   float eps,
                                                   const float* __restrict__ extra,
                                                   float* __restrict__ hout) {
    int tid = blockIdx.x * blockDim.x + threadIdx.x;
    int node = tid >> 4;
    if (node >= NN) return;
    int fc = tid & 15;
    const float4* hv = (const float4*)hin;

    int o = off[node];
    int c = cnt[node];
    float dc = dinv[node];
    float selfc = (1.0f - eps) + eps * dc * dc;

    float4 acc;
    {
        float4 hs = hv[node * 16 + fc];
        acc.x = selfc * hs.x; acc.y = selfc * hs.y;
        acc.z = selfc * hs.z; acc.w = selfc * hs.w;
    }

    int e = 0;
    for (; e + 1 < c; e += 2) {
        int s0 = csr[o + e];
        int s1 = csr[o + e + 1];
        float n0 = dinv[s0] * dc;
        float n1 = dinv[s1] * dc;
        float4 h0 = hv[s0 * 16 + fc];
        float4 h1 = hv[s1 * 16 + fc];
        acc.x += n0 * h0.x + n1 * h1.x;
        acc.y += n0 * h0.y + n1 * h1.y;
        acc.z += n0 * h0.z + n1 * h1.z;
        acc.w += n0 * h0.w + n1 * h1.w;
    }
    if (e < c) {
        int s0 = csr[o + e];
        float n0 = dinv[s0] * dc;
        float4 h0 = hv[s0 * 16 + fc];
        acc.x += n0 * h0.x; acc.y += n0 * h0.y;
        acc.z += n0 * h0.z; acc.w += n0 * h0.w;
    }
    if (extra) {
        float4 ex = ((const float4*)extra)[node * 16 + fc];
        acc.x += ex.x; acc.y += ex.y; acc.z += ex.z; acc.w += ex.w;
    }
    ((float4*)hout)[node * 16 + fc] = acc;
}

extern "C" void kernel_launch(void* const* d_in, const int* in_sizes, int n_in,
                              void* d_out, int out_size, void* d_ws, size_t ws_size,
                              hipStream_t stream) {
    const float* x  = (const float*)d_in[0];
    const int* pri  = (const int*)d_in[1];   // [2*EE]: rows then cols
    const int* sup  = (const int*)d_in[2];
    const float* w1 = (const float*)d_in[3];
    const float* b1 = (const float*)d_in[4];
    const float* w2 = (const float*)d_in[5];
    const float* b2 = (const float*)d_in[6];
    float* out = (float*)d_out;

    char* ws = (char*)d_ws;
    auto alloc = [&](size_t bytes) -> char* {
        char* p = ws;
        ws += (bytes + 255) & ~(size_t)255;
        return p;
    };
    int* cnt_p  = (int*)alloc(NN * 4);
    int* cnt_s  = (int*)alloc(NN * 4);
    int* off_p  = (int*)alloc(NN * 4);
    int* off_s  = (int*)alloc(NN * 4);
    int* cur_p  = (int*)alloc(NN * 4);
    int* cur_s  = (int*)alloc(NN * 4);
    int* bsum_p = (int*)alloc(128 * 4);
    int* bsum_s = (int*)alloc(128 * 4);
    int* csr_p  = (int*)alloc((size_t)EE * 4);
    int* csr_s  = (int*)alloc((size_t)EE * 4);
    float* dv_p1 = (float*)alloc(NN * 4);
    float* dv_p2 = (float*)alloc(NN * 4);
    float* dv_s2 = (float*)alloc(NN * 4);
    float* h1 = (float*)alloc((size_t)NN * HH * 4);  // also reused as tB after pass 2
    float* h2 = (float*)alloc((size_t)NN * HH * 4);
    float* tA = (float*)alloc((size_t)NN * HH * 4);
    float* tB = h1;

    const int* pri_row = pri;
    const int* pri_col = pri + EE;
    const int* sup_row = sup;
    const int* sup_col = sup + EE;

    const int NB_E = (EE + 255) / 256;           // 6250
    const int NB_N = (NN + 255) / 256;           // 391
    const int NB_SCAN = (NN + 1023) / 1024;      // 98
    const int NB_SPMM = (NN * 16 + 255) / 256;   // 6250
    const int NB_GEMM = NN / 32;                 // 3125

    // --- build degrees + CSR for both edge sets ---
    zero2_kernel<<<NB_N, 256, 0, stream>>>(cnt_p, cnt_s, NN);
    count_kernel<<<NB_E, 256, 0, stream>>>(pri_col, EE, cnt_p);
    count_kernel<<<NB_E, 256, 0, stream>>>(sup_col, EE, cnt_s);

    scan1_kernel<<<NB_SCAN, 256, 0, stream>>>(cnt_p, NN, off_p, bsum_p);
    scan2_kernel<<<1, 128, 0, stream>>>(bsum_p, NB_SCAN);
    scan3_kernel<<<NB_N, 256, 0, stream>>>(off_p, bsum_p, NN, cur_p);

    scan1_kernel<<<NB_SCAN, 256, 0, stream>>>(cnt_s, NN, off_s, bsum_s);
    scan2_kernel<<<1, 128, 0, stream>>>(bsum_s, NB_SCAN);
    scan3_kernel<<<NB_N, 256, 0, stream>>>(off_s, bsum_s, NN, cur_s);

    fill_kernel<<<NB_E, 256, 0, stream>>>(pri_row, pri_col, EE, cur_p, csr_p);
    fill_kernel<<<NB_E, 256, 0, stream>>>(sup_row, sup_col, EE, cur_s, csr_s);

    dinv_kernel<<<NB_N, 256, 0, stream>>>(cnt_p, cnt_s, dv_p1, dv_p2, dv_s2, NN);

    // --- dual GEMM ---
    gemm_kernel<<<NB_GEMM, 256, 0, stream>>>(x, w1, b1, w2, b2, h1, h2);

    // --- z1: two hops on pri with eps1=0.3 ---
    spmm_kernel<<<NB_SPMM, 256, 0, stream>>>(h1, off_p, cnt_p, csr_p, dv_p1, 0.3f, nullptr, tA);
    spmm_kernel<<<NB_SPMM, 256, 0, stream>>>(tA, off_p, cnt_p, csr_p, dv_p1, 0.3f, nullptr, out);

    // --- z2 branch A: two hops on sup with eps2=0.5 (h1 buffer free now -> tB) ---
    spmm_kernel<<<NB_SPMM, 256, 0, stream>>>(h2, off_s, cnt_s, csr_s, dv_s2, 0.5f, nullptr, tA);
    spmm_kernel<<<NB_SPMM, 256, 0, stream>>>(tA, off_s, cnt_s, csr_s, dv_s2, 0.5f, nullptr, tB);

    // --- z2 branch B: two hops on pri with eps2=0.5, fuse +tB into final ---
    spmm_kernel<<<NB_SPMM, 256, 0, stream>>>(h2, off_p, cnt_p, csr_p, dv_p2, 0.5f, nullptr, tA);
    spmm_kernel<<<NB_SPMM, 256, 0, stream>>>(tA, off_p, cnt_p, csr_p, dv_p2, 0.5f, tB, out + (size_t)NN * HH);
}

// Round 2
// 870.511 us; speedup vs baseline: 1.1553x; 1.1553x over previous
//
#include <hip/hip_runtime.h>

#define NN 100000
#define EE 1600000
#define FIN 128
#define HH 64

typedef unsigned int uint;
typedef unsigned short ushort;

static __device__ __forceinline__ ushort f2bf(float f) {
    uint u = __float_as_uint(f);
    uint r = (u + 0x7fffu + ((u >> 16) & 1u)) >> 16;   // RNE
    return (ushort)r;
}
static __device__ __forceinline__ float bf2f_lo(uint u) {
    return __uint_as_float(u << 16);
}
static __device__ __forceinline__ float bf2f_hi(uint u) {
    return __uint_as_float(u & 0xffff0000u);
}

// ---------------- zero counts ----------------
__global__ __launch_bounds__(256) void zero2_kernel(int* __restrict__ a, int* __restrict__ b, int n) {
    int i = blockIdx.x * blockDim.x + threadIdx.x;
    if (i < n) { a[i] = 0; b[i] = 0; }
}

// ---------------- degree count ----------------
__global__ __launch_bounds__(256) void count_kernel(const int* __restrict__ col, int E, int* __restrict__ cnt) {
    int i = blockIdx.x * blockDim.x + threadIdx.x;
    if (i < E) atomicAdd(&cnt[col[i]], 1);
}

// ---------------- exclusive scan (3-kernel) ----------------
__global__ __launch_bounds__(256) void scan1_kernel(const int* __restrict__ cnt, int n,
                                                    int* __restrict__ off, int* __restrict__ bsum) {
    __shared__ int sdata[256];
    int t = threadIdx.x;
    int base = blockIdx.x * 1024 + t * 4;
    int v0 = (base + 0 < n) ? cnt[base + 0] : 0;
    int v1 = (base + 1 < n) ? cnt[base + 1] : 0;
    int v2 = (base + 2 < n) ? cnt[base + 2] : 0;
    int v3 = (base + 3 < n) ? cnt[base + 3] : 0;
    int s = v0 + v1 + v2 + v3;
    sdata[t] = s;
    __syncthreads();
    for (int d = 1; d < 256; d <<= 1) {
        int add = (t >= d) ? sdata[t - d] : 0;
        __syncthreads();
        sdata[t] += add;
        __syncthreads();
    }
    int incl = sdata[t];
    int ex = incl - s;
    if (base + 0 < n) off[base + 0] = ex;
    if (base + 1 < n) off[base + 1] = ex + v0;
    if (base + 2 < n) off[base + 2] = ex + v0 + v1;
    if (base + 3 < n) off[base + 3] = ex + v0 + v1 + v2;
    if (t == 255) bsum[blockIdx.x] = incl;
}

__global__ __launch_bounds__(128) void scan2_kernel(int* __restrict__ bsum, int nb) {
    __shared__ int sdata[128];
    int t = threadIdx.x;
    int v = (t < nb) ? bsum[t] : 0;
    sdata[t] = v;
    __syncthreads();
    for (int d = 1; d < 128; d <<= 1) {
        int add = (t >= d) ? sdata[t - d] : 0;
        __syncthreads();
        sdata[t] += add;
        __syncthreads();
    }
    if (t < nb) bsum[t] = sdata[t] - v;
}

__global__ __launch_bounds__(256) void scan3_kernel(int* __restrict__ off, const int* __restrict__ bsum,
                                                    int n, int* __restrict__ cursor) {
    int i = blockIdx.x * blockDim.x + threadIdx.x;
    if (i < n) {
        int o = off[i] + bsum[i >> 10];
        off[i] = o;
        cursor[i] = o;
    }
}

// ---------------- CSR fill ----------------
__global__ __launch_bounds__(256) void fill_kernel(const int* __restrict__ row, const int* __restrict__ col,
                                                   int E, int* __restrict__ cursor, int* __restrict__ csr) {
    int i = blockIdx.x * blockDim.x + threadIdx.x;
    if (i < E) {
        int c = col[i];
        int p = atomicAdd(&cursor[c], 1);
        csr[p] = row[i];
    }
}

// ---------------- dinv (3 configs) ----------------
__global__ __launch_bounds__(256) void dinv_kernel(const int* __restrict__ cp, const int* __restrict__ cs,
                                                   float* __restrict__ dp1, float* __restrict__ dp2,
                                                   float* __restrict__ ds2, int n) {
    int i = blockIdx.x * blockDim.x + threadIdx.x;
    if (i < n) {
        float fp = (float)cp[i];
        float fs = (float)cs[i];
        dp1[i] = rsqrtf(fp + 0.3f);
        dp2[i] = rsqrtf(fp + 0.5f);
        ds2[i] = rsqrtf(fs + 0.5f);
    }
}

// ---------------- fused dual GEMM + bf16 g-table epilogue ----------------
// block = 512 (8 waves), each wave 8 rows -> 64 rows/block. lane = output col.
// W (both) in 64 KB LDS; LDS amortized over 8 waves -> 2 blocks/CU = 16 waves/CU.
__global__ __launch_bounds__(512, 4) void gemm_kernel(const float* __restrict__ x,
                                                      const float* __restrict__ w1, const float* __restrict__ b1,
                                                      const float* __restrict__ w2, const float* __restrict__ b2,
                                                      const float* __restrict__ dp1, const float* __restrict__ dp2,
                                                      const float* __restrict__ ds2,
                                                      float* __restrict__ h1, float* __restrict__ h2,
                                                      ushort* __restrict__ g1, ushort* __restrict__ g2s,
                                                      ushort* __restrict__ g2p) {
    __shared__ float4 Wp[2][32][64];  // 64 KB
    int t = threadIdx.x;
    const float4* w1v = (const float4*)w1;
    const float4* w2v = (const float4*)w2;
    // lane-consecutive j -> conflict-minimal LDS stores
    for (int f = t; f < 4096; f += 512) {
        int j  = f & 63;
        int kk = (f >> 6) & 31;
        int s  = f >> 11;
        Wp[s][kk][j] = (s == 0) ? w1v[j * 32 + kk] : w2v[j * 32 + kk];
    }
    __syncthreads();

    int lane = t & 63;
    int wave = t >> 6;
    int row0 = blockIdx.x * 64 + wave * 8;
    float bb1 = b1[lane], bb2 = b2[lane];
    float acc1[8], acc2[8];
#pragma unroll
    for (int i = 0; i < 8; i++) { acc1[i] = bb1; acc2[i] = bb2; }

    int xr[8];
#pragma unroll
    for (int i = 0; i < 8; i++) {
        int r = row0 + i;
        xr[i] = (r < NN ? r : NN - 1) * 32;
    }

    const float4* xv = (const float4*)x;
    for (int kk = 0; kk < 32; kk += 2) {
        float4 xq[16];
#pragma unroll
        for (int i = 0; i < 8; i++) {
            xq[i]     = xv[xr[i] + kk];
            xq[i + 8] = xv[xr[i] + kk + 1];
        }
        float4 wa1 = Wp[0][kk][lane];
        float4 wa2 = Wp[1][kk][lane];
        float4 wb1 = Wp[0][kk + 1][lane];
        float4 wb2 = Wp[1][kk + 1][lane];
#pragma unroll
        for (int i = 0; i < 8; i++) {
            acc1[i] += xq[i].x * wa1.x + xq[i].y * wa1.y + xq[i].z * wa1.z + xq[i].w * wa1.w;
            acc2[i] += xq[i].x * wa2.x + xq[i].y * wa2.y + xq[i].z * wa2.z + xq[i].w * wa2.w;
            acc1[i] += xq[i + 8].x * wb1.x + xq[i + 8].y * wb1.y + xq[i + 8].z * wb1.z + xq[i + 8].w * wb1.w;
            acc2[i] += xq[i + 8].x * wb2.x + xq[i + 8].y * wb2.y + xq[i + 8].z * wb2.z + xq[i + 8].w * wb2.w;
        }
    }

#pragma unroll
    for (int i = 0; i < 8; i++) {
        int r = row0 + i;
        if (r < NN) {
            float a1 = acc1[i], a2 = acc2[i];
            h1[r * 64 + lane] = a1;
            h2[r * 64 + lane] = a2;
            g1 [r * 64 + lane] = f2bf(a1 * dp1[r]);
            g2s[r * 64 + lane] = f2bf(a2 * ds2[r]);
            g2p[r * 64 + lane] = f2bf(a2 * dp2[r]);
        }
    }
}

// ---------------- SpMM pass, bf16 source-scaled gather table ----------------
// hout[c] = ((1-eps)+eps*dc^2)*hin[c] + dc * sum_e g[src]  (+ extra[c])
// gout[c] = bf16(dnext[c] * hout[c])   (optional, feeds the next hop)
// 8 threads/node, each owns 8 features. g row = 64 x bf16 = 128 B.
__global__ __launch_bounds__(256) void spmm_kernel(const float* __restrict__ hin,
                                                   const uint* __restrict__ gin,
                                                   const int* __restrict__ off,
                                                   const int* __restrict__ cnt,
                                                   const int* __restrict__ csr,
                                                   const float* __restrict__ dinv,
                                                   float eps,
                                                   const float* __restrict__ extra,
                                                   float* __restrict__ hout,
                                                   ushort* __restrict__ gout,
                                                   const float* __restrict__ dnext) {
    int tid = blockIdx.x * blockDim.x + threadIdx.x;
    int node = tid >> 3;
    if (node >= NN) return;
    int fc = tid & 7;                      // features fc*8 .. fc*8+7
    const uint4* gv = (const uint4*)gin;   // 8 bf16 per uint4

    int o = off[node];
    int c = cnt[node];
    float dc = dinv[node];
    float selfc = (1.0f - eps) + eps * dc * dc;

    float s0f = 0, s1f = 0, s2f = 0, s3f = 0, s4f = 0, s5f = 0, s6f = 0, s7f = 0;

    int e = 0;
    for (; e + 1 < c; e += 2) {
        int n0 = csr[o + e];
        int n1 = csr[o + e + 1];
        uint4 q0 = gv[n0 * 8 + fc];
        uint4 q1 = gv[n1 * 8 + fc];
        s0f += bf2f_lo(q0.x) + bf2f_lo(q1.x);
        s1f += bf2f_hi(q0.x) + bf2f_hi(q1.x);
        s2f += bf2f_lo(q0.y) + bf2f_lo(q1.y);
        s3f += bf2f_hi(q0.y) + bf2f_hi(q1.y);
        s4f += bf2f_lo(q0.z) + bf2f_lo(q1.z);
        s5f += bf2f_hi(q0.z) + bf2f_hi(q1.z);
        s6f += bf2f_lo(q0.w) + bf2f_lo(q1.w);
        s7f += bf2f_hi(q0.w) + bf2f_hi(q1.w);
    }
    if (e < c) {
        int n0 = csr[o + e];
        uint4 q0 = gv[n0 * 8 + fc];
        s0f += bf2f_lo(q0.x);
        s1f += bf2f_hi(q0.x);
        s2f += bf2f_lo(q0.y);
        s3f += bf2f_hi(q0.y);
        s4f += bf2f_lo(q0.z);
        s5f += bf2f_hi(q0.z);
        s6f += bf2f_lo(q0.w);
        s7f += bf2f_hi(q0.w);
    }

    const float4* hv = (const float4*)hin;
    float4 ha = hv[node * 16 + fc * 2];
    float4 hb = hv[node * 16 + fc * 2 + 1];
    float o0 = selfc * ha.x + dc * s0f;
    float o1 = selfc * ha.y + dc * s1f;
    float o2 = selfc * ha.z + dc * s2f;
    float o3 = selfc * ha.w + dc * s3f;
    float o4 = selfc * hb.x + dc * s4f;
    float o5 = selfc * hb.y + dc * s5f;
    float o6 = selfc * hb.z + dc * s6f;
    float o7 = selfc * hb.w + dc * s7f;

    if (extra) {
        const float4* ev = (const float4*)extra;
        float4 ea = ev[node * 16 + fc * 2];
        float4 eb = ev[node * 16 + fc * 2 + 1];
        o0 += ea.x; o1 += ea.y; o2 += ea.z; o3 += ea.w;
        o4 += eb.x; o5 += eb.y; o6 += eb.z; o7 += eb.w;
    }

    float4* ho = (float4*)hout;
    ho[node * 16 + fc * 2]     = make_float4(o0, o1, o2, o3);
    ho[node * 16 + fc * 2 + 1] = make_float4(o4, o5, o6, o7);

    if (gout) {
        float dn = dnext[node];
        uint4 gq;
        gq.x = (uint)f2bf(o0 * dn) | ((uint)f2bf(o1 * dn) << 16);
        gq.y = (uint)f2bf(o2 * dn) | ((uint)f2bf(o3 * dn) << 16);
        gq.z = (uint)f2bf(o4 * dn) | ((uint)f2bf(o5 * dn) << 16);
        gq.w = (uint)f2bf(o6 * dn) | ((uint)f2bf(o7 * dn) << 16);
        ((uint4*)gout)[node * 8 + fc] = gq;
    }
}

extern "C" void kernel_launch(void* const* d_in, const int* in_sizes, int n_in,
                              void* d_out, int out_size, void* d_ws, size_t ws_size,
                              hipStream_t stream) {
    const float* x  = (const float*)d_in[0];
    const int* pri  = (const int*)d_in[1];
    const int* sup  = (const int*)d_in[2];
    const float* w1 = (const float*)d_in[3];
    const float* b1 = (const float*)d_in[4];
    const float* w2 = (const float*)d_in[5];
    const float* b2 = (const float*)d_in[6];
    float* out = (float*)d_out;

    char* ws = (char*)d_ws;
    auto alloc = [&](size_t bytes) -> char* {
        char* p = ws;
        ws += (bytes + 255) & ~(size_t)255;
        return p;
    };
    int* cnt_p  = (int*)alloc(NN * 4);
    int* cnt_s  = (int*)alloc(NN * 4);
    int* off_p  = (int*)alloc(NN * 4);
    int* off_s  = (int*)alloc(NN * 4);
    int* cur_p  = (int*)alloc(NN * 4);
    int* cur_s  = (int*)alloc(NN * 4);
    int* bsum_p = (int*)alloc(128 * 4);
    int* bsum_s = (int*)alloc(128 * 4);
    int* csr_p  = (int*)alloc((size_t)EE * 4);
    int* csr_s  = (int*)alloc((size_t)EE * 4);
    float* dv_p1 = (float*)alloc(NN * 4);
    float* dv_p2 = (float*)alloc(NN * 4);
    float* dv_s2 = (float*)alloc(NN * 4);
    float* h1 = (float*)alloc((size_t)NN * HH * 4);   // also tB later
    float* h2 = (float*)alloc((size_t)NN * HH * 4);
    float* tA = (float*)alloc((size_t)NN * HH * 4);
    ushort* g1  = (ushort*)alloc((size_t)NN * HH * 2);  // also gS later
    ushort* gt  = (ushort*)alloc((size_t)NN * HH * 2);  // also gP later
    ushort* g2s = (ushort*)alloc((size_t)NN * HH * 2);
    ushort* g2p = (ushort*)alloc((size_t)NN * HH * 2);
    float* tB = h1;
    ushort* gS = g1;
    ushort* gP = gt;

    const int* pri_row = pri;
    const int* pri_col = pri + EE;
    const int* sup_row = sup;
    const int* sup_col = sup + EE;

    const int NB_E = (EE + 255) / 256;
    const int NB_N = (NN + 255) / 256;
    const int NB_SCAN = (NN + 1023) / 1024;
    const int NB_SPMM = (NN * 8 + 255) / 256;    // 3125
    const int NB_GEMM = (NN + 63) / 64;          // 1563

    // --- degrees + CSR ---
    zero2_kernel<<<NB_N, 256, 0, stream>>>(cnt_p, cnt_s, NN);
    count_kernel<<<NB_E, 256, 0, stream>>>(pri_col, EE, cnt_p);
    count_kernel<<<NB_E, 256, 0, stream>>>(sup_col, EE, cnt_s);

    scan1_kernel<<<NB_SCAN, 256, 0, stream>>>(cnt_p, NN, off_p, bsum_p);
    scan2_kernel<<<1, 128, 0, stream>>>(bsum_p, NB_SCAN);
    scan3_kernel<<<NB_N, 256, 0, stream>>>(off_p, bsum_p, NN, cur_p);

    scan1_kernel<<<NB_SCAN, 256, 0, stream>>>(cnt_s, NN, off_s, bsum_s);
    scan2_kernel<<<1, 128, 0, stream>>>(bsum_s, NB_SCAN);
    scan3_kernel<<<NB_N, 256, 0, stream>>>(off_s, bsum_s, NN, cur_s);

    fill_kernel<<<NB_E, 256, 0, stream>>>(pri_row, pri_col, EE, cur_p, csr_p);
    fill_kernel<<<NB_E, 256, 0, stream>>>(sup_row, sup_col, EE, cur_s, csr_s);

    dinv_kernel<<<NB_N, 256, 0, stream>>>(cnt_p, cnt_s, dv_p1, dv_p2, dv_s2, NN);

    // --- dual GEMM + g tables ---
    gemm_kernel<<<NB_GEMM, 512, 0, stream>>>(x, w1, b1, w2, b2, dv_p1, dv_p2, dv_s2,
                                             h1, h2, g1, g2s, g2p);

    // --- z1: two hops on pri, eps=0.3 ---
    spmm_kernel<<<NB_SPMM, 256, 0, stream>>>(h1, (const uint*)g1, off_p, cnt_p, csr_p, dv_p1, 0.3f,
                                             nullptr, tA, gt, dv_p1);
    spmm_kernel<<<NB_SPMM, 256, 0, stream>>>(tA, (const uint*)gt, off_p, cnt_p, csr_p, dv_p1, 0.3f,
                                             nullptr, out, nullptr, nullptr);

    // --- z2 branch A: two hops on sup, eps=0.5 ---
    spmm_kernel<<<NB_SPMM, 256, 0, stream>>>(h2, (const uint*)g2s, off_s, cnt_s, csr_s, dv_s2, 0.5f,
                                             nullptr, tA, gS, dv_s2);
    spmm_kernel<<<NB_SPMM, 256, 0, stream>>>(tA, (const uint*)gS, off_s, cnt_s, csr_s, dv_s2, 0.5f,
                                             nullptr, tB, nullptr, nullptr);

    // --- z2 branch B: two hops on pri, eps=0.5, fuse +tB ---
    spmm_kernel<<<NB_SPMM, 256, 0, stream>>>(h2, (const uint*)g2p, off_p, cnt_p, csr_p, dv_p2, 0.5f,
                                             nullptr, tA, gP, dv_p2);
    spmm_kernel<<<NB_SPMM, 256, 0, stream>>>(tA, (const uint*)gP, off_p, cnt_p, csr_p, dv_p2, 0.5f,
                                             tB, out + (size_t)NN * HH, nullptr, nullptr);
}

// Round 3
// 737.397 us; speedup vs baseline: 1.3638x; 1.1805x over previous
//
#include <hip/hip_runtime.h>

#define NN 100000
#define EE 1600000
#define FIN 128
#define HH 64

typedef unsigned int uint;
typedef unsigned short ushort;
typedef __attribute__((ext_vector_type(8))) short short8;
typedef __attribute__((ext_vector_type(4))) float float4a;

union FragU { uint4 u; short8 s; };

static __device__ __forceinline__ ushort f2bf(float f) {
    uint u = __float_as_uint(f);
    uint r = (u + 0x7fffu + ((u >> 16) & 1u)) >> 16;   // RNE
    return (ushort)r;
}
static __device__ __forceinline__ uint pack2bf(float a, float b) {
    return (uint)f2bf(a) | ((uint)f2bf(b) << 16);
}
static __device__ __forceinline__ float bf2f_lo(uint u) {
    return __uint_as_float(u << 16);
}
static __device__ __forceinline__ float bf2f_hi(uint u) {
    return __uint_as_float(u & 0xffff0000u);
}

// ---------------- zero counts ----------------
__global__ __launch_bounds__(256) void zero2_kernel(int* __restrict__ a, int* __restrict__ b, int n) {
    int i = blockIdx.x * blockDim.x + threadIdx.x;
    if (i < n) { a[i] = 0; b[i] = 0; }
}

// ---------------- degree count ----------------
__global__ __launch_bounds__(256) void count_kernel(const int* __restrict__ col, int E, int* __restrict__ cnt) {
    int i = blockIdx.x * blockDim.x + threadIdx.x;
    if (i < E) atomicAdd(&cnt[col[i]], 1);
}

// ---------------- exclusive scan (3-kernel) ----------------
__global__ __launch_bounds__(256) void scan1_kernel(const int* __restrict__ cnt, int n,
                                                    int* __restrict__ off, int* __restrict__ bsum) {
    __shared__ int sdata[256];
    int t = threadIdx.x;
    int base = blockIdx.x * 1024 + t * 4;
    int v0 = (base + 0 < n) ? cnt[base + 0] : 0;
    int v1 = (base + 1 < n) ? cnt[base + 1] : 0;
    int v2 = (base + 2 < n) ? cnt[base + 2] : 0;
    int v3 = (base + 3 < n) ? cnt[base + 3] : 0;
    int s = v0 + v1 + v2 + v3;
    sdata[t] = s;
    __syncthreads();
    for (int d = 1; d < 256; d <<= 1) {
        int add = (t >= d) ? sdata[t - d] : 0;
        __syncthreads();
        sdata[t] += add;
        __syncthreads();
    }
    int incl = sdata[t];
    int ex = incl - s;
    if (base + 0 < n) off[base + 0] = ex;
    if (base + 1 < n) off[base + 1] = ex + v0;
    if (base + 2 < n) off[base + 2] = ex + v0 + v1;
    if (base + 3 < n) off[base + 3] = ex + v0 + v1 + v2;
    if (t == 255) bsum[blockIdx.x] = incl;
}

__global__ __launch_bounds__(128) void scan2_kernel(int* __restrict__ bsum, int nb) {
    __shared__ int sdata[128];
    int t = threadIdx.x;
    int v = (t < nb) ? bsum[t] : 0;
    sdata[t] = v;
    __syncthreads();
    for (int d = 1; d < 128; d <<= 1) {
        int add = (t >= d) ? sdata[t - d] : 0;
        __syncthreads();
        sdata[t] += add;
        __syncthreads();
    }
    if (t < nb) bsum[t] = sdata[t] - v;
}

__global__ __launch_bounds__(256) void scan3_kernel(int* __restrict__ off, const int* __restrict__ bsum,
                                                    int n, int* __restrict__ cursor) {
    int i = blockIdx.x * blockDim.x + threadIdx.x;
    if (i < n) {
        int o = off[i] + bsum[i >> 10];
        off[i] = o;
        cursor[i] = o;
    }
}

// ---------------- CSR fill ----------------
__global__ __launch_bounds__(256) void fill_kernel(const int* __restrict__ row, const int* __restrict__ col,
                                                   int E, int* __restrict__ cursor, int* __restrict__ csr) {
    int i = blockIdx.x * blockDim.x + threadIdx.x;
    if (i < E) {
        int c = col[i];
        int p = atomicAdd(&cursor[c], 1);
        csr[p] = row[i];
    }
}

// ---------------- dinv (3 configs) ----------------
__global__ __launch_bounds__(256) void dinv_kernel(const int* __restrict__ cp, const int* __restrict__ cs,
                                                   float* __restrict__ dp1, float* __restrict__ dp2,
                                                   float* __restrict__ ds2, int n) {
    int i = blockIdx.x * blockDim.x + threadIdx.x;
    if (i < n) {
        float fp = (float)cp[i];
        float fs = (float)cs[i];
        dp1[i] = rsqrtf(fp + 0.3f);
        dp2[i] = rsqrtf(fp + 0.5f);
        ds2[i] = rsqrtf(fs + 0.5f);
    }
}

// ---------------- W -> bf16 B-fragment-major conversion ----------------
// Combined W[c][k]: c<64 -> w1[c], else w2[c-64]. Fragment for mfma 16x16x32 B-operand:
// lane holds W[ct*16 + (lane&15)][ks*32 + (lane>>4)*8 .. +8]. Layout: [(ct*4+ks)*64 + lane] x 16B.
__global__ __launch_bounds__(256) void wconv_kernel(const float* __restrict__ w1,
                                                    const float* __restrict__ w2,
                                                    uint4* __restrict__ wfrag) {
    int u = blockIdx.x * 256 + threadIdx.x;   // 0..2047
    if (u >= 2048) return;
    int lane = u & 63;
    int ks   = (u >> 6) & 3;
    int ct   = u >> 8;
    int c    = ct * 16 + (lane & 15);
    int k0   = ks * 32 + (lane >> 4) * 8;
    const float* src = (c < 64) ? (w1 + c * 128 + k0) : (w2 + (c - 64) * 128 + k0);
    float4 p0 = ((const float4*)src)[0];
    float4 p1 = ((const float4*)src)[1];
    uint4 q;
    q.x = pack2bf(p0.x, p0.y);
    q.y = pack2bf(p0.z, p0.w);
    q.z = pack2bf(p1.x, p1.y);
    q.w = pack2bf(p1.z, p1.w);
    wfrag[u] = q;
}

// ---------------- MFMA dual GEMM + g-table epilogue ----------------
// block = 256 (4 waves), 128 rows/block, N=128 combined cols (waves 0-1 -> h1, 2-3 -> h2).
// A staged in LDS fragment-major with sigma(m,c)=17c+m swizzle; B-frags in registers.
__global__ __launch_bounds__(256) void gemm_kernel(const float* __restrict__ x,
                                                   const uint4* __restrict__ wfrag,
                                                   const float* __restrict__ b1, const float* __restrict__ b2,
                                                   const float* __restrict__ dp1, const float* __restrict__ dp2,
                                                   const float* __restrict__ ds2,
                                                   float* __restrict__ h1, float* __restrict__ h2,
                                                   ushort* __restrict__ g1, ushort* __restrict__ g2s,
                                                   ushort* __restrict__ g2p) {
    __shared__ uint4 alds[32 * 68];   // 8 row-tiles x 4 ksteps, 68-unit stride = 34 KB
    int t = threadIdx.x;
    int lane = t & 63;
    int wave = t >> 6;
    int row0 = blockIdx.x * 128;

    // --- B fragments: wave w covers col-tiles 2w, 2w+1 ---
    FragU bfrag[2][4];
#pragma unroll
    for (int ctl = 0; ctl < 2; ctl++)
#pragma unroll
        for (int ks = 0; ks < 4; ks++)
            bfrag[ctl][ks].u = wfrag[((wave * 2 + ctl) * 4 + ks) * 64 + lane];

    // --- stage x tile: fp32 -> bf16 -> LDS fragment-major ---
    {
        int m = t >> 4;        // 0..15: row within 16-row slab
        int g = t & 15;        // 8-float k-group
        const float4* xv = (const float4*)x;
#pragma unroll
        for (int s = 0; s < 8; s++) {
            int r = row0 + s * 16 + m;
            int rc = (r < NN) ? r : (NN - 1);
            float4 p0 = xv[rc * 32 + g * 2];
            float4 p1 = xv[rc * 32 + g * 2 + 1];
            uint4 q;
            q.x = pack2bf(p0.x, p0.y);
            q.y = pack2bf(p0.z, p0.w);
            q.z = pack2bf(p1.x, p1.y);
            q.w = pack2bf(p1.z, p1.w);
            alds[(s * 4 + (g >> 2)) * 68 + (g & 3) * 17 + m] = q;
        }
    }
    __syncthreads();

    // --- accumulators init with bias ---
    int cA = (wave * 2 + 0) * 16 + (lane & 15);
    int cB = cA + 16;
    float biasA = (wave < 2) ? b1[cA] : b2[cA - 64];
    float biasB = (wave < 2) ? b1[cB] : b2[cB - 64];
    float4a acc[8][2];
#pragma unroll
    for (int rt = 0; rt < 8; rt++) {
        acc[rt][0] = float4a{biasA, biasA, biasA, biasA};
        acc[rt][1] = float4a{biasB, biasB, biasB, biasB};
    }

    int quad = lane >> 4;
    int asig = quad * 17 + (lane & 15);
#pragma unroll
    for (int rt = 0; rt < 8; rt++) {
        FragU af[4];
#pragma unroll
        for (int ks = 0; ks < 4; ks++)
            af[ks].u = alds[(rt * 4 + ks) * 68 + asig];
#pragma unroll
        for (int ks = 0; ks < 4; ks++) {
            acc[rt][0] = __builtin_amdgcn_mfma_f32_16x16x32_bf16(af[ks].s, bfrag[0][ks].s, acc[rt][0], 0, 0, 0);
            acc[rt][1] = __builtin_amdgcn_mfma_f32_16x16x32_bf16(af[ks].s, bfrag[1][ks].s, acc[rt][1], 0, 0, 0);
        }
    }

    // --- epilogue: C/D layout col=lane&15, row=quad*4+reg ---
#pragma unroll
    for (int rt = 0; rt < 8; rt++) {
        int rb = row0 + rt * 16 + quad * 4;
#pragma unroll
        for (int ctl = 0; ctl < 2; ctl++) {
            int c = (wave * 2 + ctl) * 16 + (lane & 15);
#pragma unroll
            for (int reg = 0; reg < 4; reg++) {
                int r = rb + reg;
                if (r >= NN) continue;
                float v = acc[rt][ctl][reg];
                if (wave < 2) {
                    h1[r * 64 + c] = v;
                    g1[r * 64 + c] = f2bf(v * dp1[r]);
                } else {
                    int cc = c - 64;
                    h2[r * 64 + cc]  = v;
                    g2s[r * 64 + cc] = f2bf(v * ds2[r]);
                    g2p[r * 64 + cc] = f2bf(v * dp2[r]);
                }
            }
        }
    }
}

// ---------------- SpMM pass, bf16 source-scaled gather table ----------------
// hout[c] = ((1-eps)+eps*dc^2)*hin[c] + dc * sum_e g[src]  (+ extra[c])
// gout[c] = bf16(dnext[c] * hout[c]). 8 threads/node, 16B gathers, x4 unroll.
__global__ __launch_bounds__(256) void spmm_kernel(const float* __restrict__ hin,
                                                   const uint* __restrict__ gin,
                                                   const int* __restrict__ off,
                                                   const int* __restrict__ cnt,
                                                   const int* __restrict__ csr,
                                                   const float* __restrict__ dinv,
                                                   float eps,
                                                   const float* __restrict__ extra,
                                                   float* __restrict__ hout,
                                                   ushort* __restrict__ gout,
                                                   const float* __restrict__ dnext) {
    int tid = blockIdx.x * blockDim.x + threadIdx.x;
    int node = tid >> 3;
    if (node >= NN) return;
    int fc = tid & 7;
    const uint4* gv = (const uint4*)gin;

    int o = off[node];
    int c = cnt[node];
    float dc = dinv[node];
    float selfc = (1.0f - eps) + eps * dc * dc;

    float s0f = 0, s1f = 0, s2f = 0, s3f = 0, s4f = 0, s5f = 0, s6f = 0, s7f = 0;

    int e = 0;
    for (; e + 3 < c; e += 4) {
        int n0 = csr[o + e];
        int n1 = csr[o + e + 1];
        int n2 = csr[o + e + 2];
        int n3 = csr[o + e + 3];
        uint4 q0 = gv[n0 * 8 + fc];
        uint4 q1 = gv[n1 * 8 + fc];
        uint4 q2 = gv[n2 * 8 + fc];
        uint4 q3 = gv[n3 * 8 + fc];
        s0f += (bf2f_lo(q0.x) + bf2f_lo(q1.x)) + (bf2f_lo(q2.x) + bf2f_lo(q3.x));
        s1f += (bf2f_hi(q0.x) + bf2f_hi(q1.x)) + (bf2f_hi(q2.x) + bf2f_hi(q3.x));
        s2f += (bf2f_lo(q0.y) + bf2f_lo(q1.y)) + (bf2f_lo(q2.y) + bf2f_lo(q3.y));
        s3f += (bf2f_hi(q0.y) + bf2f_hi(q1.y)) + (bf2f_hi(q2.y) + bf2f_hi(q3.y));
        s4f += (bf2f_lo(q0.z) + bf2f_lo(q1.z)) + (bf2f_lo(q2.z) + bf2f_lo(q3.z));
        s5f += (bf2f_hi(q0.z) + bf2f_hi(q1.z)) + (bf2f_hi(q2.z) + bf2f_hi(q3.z));
        s6f += (bf2f_lo(q0.w) + bf2f_lo(q1.w)) + (bf2f_lo(q2.w) + bf2f_lo(q3.w));
        s7f += (bf2f_hi(q0.w) + bf2f_hi(q1.w)) + (bf2f_hi(q2.w) + bf2f_hi(q3.w));
    }
    for (; e < c; e++) {
        int n0 = csr[o + e];
        uint4 q0 = gv[n0 * 8 + fc];
        s0f += bf2f_lo(q0.x);
        s1f += bf2f_hi(q0.x);
        s2f += bf2f_lo(q0.y);
        s3f += bf2f_hi(q0.y);
        s4f += bf2f_lo(q0.z);
        s5f += bf2f_hi(q0.z);
        s6f += bf2f_lo(q0.w);
        s7f += bf2f_hi(q0.w);
    }

    const float4* hv = (const float4*)hin;
    float4 ha = hv[node * 16 + fc * 2];
    float4 hb = hv[node * 16 + fc * 2 + 1];
    float o0 = selfc * ha.x + dc * s0f;
    float o1 = selfc * ha.y + dc * s1f;
    float o2 = selfc * ha.z + dc * s2f;
    float o3 = selfc * ha.w + dc * s3f;
    float o4 = selfc * hb.x + dc * s4f;
    float o5 = selfc * hb.y + dc * s5f;
    float o6 = selfc * hb.z + dc * s6f;
    float o7 = selfc * hb.w + dc * s7f;

    if (extra) {
        const float4* ev = (const float4*)extra;
        float4 ea = ev[node * 16 + fc * 2];
        float4 eb = ev[node * 16 + fc * 2 + 1];
        o0 += ea.x; o1 += ea.y; o2 += ea.z; o3 += ea.w;
        o4 += eb.x; o5 += eb.y; o6 += eb.z; o7 += eb.w;
    }

    float4* ho = (float4*)hout;
    ho[node * 16 + fc * 2]     = make_float4(o0, o1, o2, o3);
    ho[node * 16 + fc * 2 + 1] = make_float4(o4, o5, o6, o7);

    if (gout) {
        float dn = dnext[node];
        uint4 gq;
        gq.x = pack2bf(o0 * dn, o1 * dn);
        gq.y = pack2bf(o2 * dn, o3 * dn);
        gq.z = pack2bf(o4 * dn, o5 * dn);
        gq.w = pack2bf(o6 * dn, o7 * dn);
        ((uint4*)gout)[node * 8 + fc] = gq;
    }
}

extern "C" void kernel_launch(void* const* d_in, const int* in_sizes, int n_in,
                              void* d_out, int out_size, void* d_ws, size_t ws_size,
                              hipStream_t stream) {
    const float* x  = (const float*)d_in[0];
    const int* pri  = (const int*)d_in[1];
    const int* sup  = (const int*)d_in[2];
    const float* w1 = (const float*)d_in[3];
    const float* b1 = (const float*)d_in[4];
    const float* w2 = (const float*)d_in[5];
    const float* b2 = (const float*)d_in[6];
    float* out = (float*)d_out;

    char* ws = (char*)d_ws;
    auto alloc = [&](size_t bytes) -> char* {
        char* p = ws;
        ws += (bytes + 255) & ~(size_t)255;
        return p;
    };
    int* cnt_p  = (int*)alloc(NN * 4);
    int* cnt_s  = (int*)alloc(NN * 4);
    int* off_p  = (int*)alloc(NN * 4);
    int* off_s  = (int*)alloc(NN * 4);
    int* cur_p  = (int*)alloc(NN * 4);
    int* cur_s  = (int*)alloc(NN * 4);
    int* bsum_p = (int*)alloc(128 * 4);
    int* bsum_s = (int*)alloc(128 * 4);
    int* csr_p  = (int*)alloc((size_t)EE * 4);
    int* csr_s  = (int*)alloc((size_t)EE * 4);
    float* dv_p1 = (float*)alloc(NN * 4);
    float* dv_p2 = (float*)alloc(NN * 4);
    float* dv_s2 = (float*)alloc(NN * 4);
    uint4* wfrag = (uint4*)alloc(2048 * 16);
    float* h1 = (float*)alloc((size_t)NN * HH * 4);   // also tB later
    float* h2 = (float*)alloc((size_t)NN * HH * 4);
    float* tA = (float*)alloc((size_t)NN * HH * 4);
    ushort* g1  = (ushort*)alloc((size_t)NN * HH * 2);  // also gS later
    ushort* gt  = (ushort*)alloc((size_t)NN * HH * 2);  // also gP later
    ushort* g2s = (ushort*)alloc((size_t)NN * HH * 2);
    ushort* g2p = (ushort*)alloc((size_t)NN * HH * 2);
    float* tB = h1;
    ushort* gS = g1;
    ushort* gP = gt;

    const int* pri_row = pri;
    const int* pri_col = pri + EE;
    const int* sup_row = sup;
    const int* sup_col = sup + EE;

    const int NB_E = (EE + 255) / 256;
    const int NB_N = (NN + 255) / 256;
    const int NB_SCAN = (NN + 1023) / 1024;
    const int NB_SPMM = (NN * 8 + 255) / 256;    // 3125
    const int NB_GEMM = (NN + 127) / 128;        // 782

    // --- degrees + CSR ---
    zero2_kernel<<<NB_N, 256, 0, stream>>>(cnt_p, cnt_s, NN);
    count_kernel<<<NB_E, 256, 0, stream>>>(pri_col, EE, cnt_p);
    count_kernel<<<NB_E, 256, 0, stream>>>(sup_col, EE, cnt_s);

    scan1_kernel<<<NB_SCAN, 256, 0, stream>>>(cnt_p, NN, off_p, bsum_p);
    scan2_kernel<<<1, 128, 0, stream>>>(bsum_p, NB_SCAN);
    scan3_kernel<<<NB_N, 256, 0, stream>>>(off_p, bsum_p, NN, cur_p);

    scan1_kernel<<<NB_SCAN, 256, 0, stream>>>(cnt_s, NN, off_s, bsum_s);
    scan2_kernel<<<1, 128, 0, stream>>>(bsum_s, NB_SCAN);
    scan3_kernel<<<NB_N, 256, 0, stream>>>(off_s, bsum_s, NN, cur_s);

    fill_kernel<<<NB_E, 256, 0, stream>>>(pri_row, pri_col, EE, cur_p, csr_p);
    fill_kernel<<<NB_E, 256, 0, stream>>>(sup_row, sup_col, EE, cur_s, csr_s);

    dinv_kernel<<<NB_N, 256, 0, stream>>>(cnt_p, cnt_s, dv_p1, dv_p2, dv_s2, NN);

    // --- W conversion + MFMA dual GEMM ---
    wconv_kernel<<<8, 256, 0, stream>>>(w1, w2, wfrag);
    gemm_kernel<<<NB_GEMM, 256, 0, stream>>>(x, wfrag, b1, b2, dv_p1, dv_p2, dv_s2,
                                             h1, h2, g1, g2s, g2p);

    // --- z1: two hops on pri, eps=0.3 ---
    spmm_kernel<<<NB_SPMM, 256, 0, stream>>>(h1, (const uint*)g1, off_p, cnt_p, csr_p, dv_p1, 0.3f,
                                             nullptr, tA, gt, dv_p1);
    spmm_kernel<<<NB_SPMM, 256, 0, stream>>>(tA, (const uint*)gt, off_p, cnt_p, csr_p, dv_p1, 0.3f,
                                             nullptr, out, nullptr, nullptr);

    // --- z2 branch A: two hops on sup, eps=0.5 ---
    spmm_kernel<<<NB_SPMM, 256, 0, stream>>>(h2, (const uint*)g2s, off_s, cnt_s, csr_s, dv_s2, 0.5f,
                                             nullptr, tA, gS, dv_s2);
    spmm_kernel<<<NB_SPMM, 256, 0, stream>>>(tA, (const uint*)gS, off_s, cnt_s, csr_s, dv_s2, 0.5f,
                                             nullptr, tB, nullptr, nullptr);

    // --- z2 branch B: two hops on pri, eps=0.5, fuse +tB ---
    spmm_kernel<<<NB_SPMM, 256, 0, stream>>>(h2, (const uint*)g2p, off_p, cnt_p, csr_p, dv_p2, 0.5f,
                                             nullptr, tA, gP, dv_p2);
    spmm_kernel<<<NB_SPMM, 256, 0, stream>>>(tA, (const uint*)gP, off_p, cnt_p, csr_p, dv_p2, 0.5f,
                                             tB, out + (size_t)NN * HH, nullptr, nullptr);
}

// Round 4
// 519.044 us; speedup vs baseline: 1.9376x; 1.4207x over previous
//
#include <hip/hip_runtime.h>

#define NN 100000
#define EE 1600000
#define FIN 128
#define HH 64
#define NBKT 782          // ceil(NN/128) coarse buckets
#define SCHUNK 8192       // edges per block in hist/scatter passes

typedef unsigned int uint;
typedef unsigned short ushort;
typedef __attribute__((ext_vector_type(8))) short short8;
typedef __attribute__((ext_vector_type(4))) float float4a;

union FragU { uint4 u; short8 s; };

static __device__ __forceinline__ ushort f2bf(float f) {
    uint u = __float_as_uint(f);
    uint r = (u + 0x7fffu + ((u >> 16) & 1u)) >> 16;   // RNE
    return (ushort)r;
}
static __device__ __forceinline__ uint pack2bf(float a, float b) {
    return (uint)f2bf(a) | ((uint)f2bf(b) << 16);
}
static __device__ __forceinline__ float bf2f_lo(uint u) {
    return __uint_as_float(u << 16);
}
static __device__ __forceinline__ float bf2f_hi(uint u) {
    return __uint_as_float(u & 0xffff0000u);
}

// ---------------- zero two int arrays ----------------
__global__ __launch_bounds__(256) void zero2_kernel(int* __restrict__ a, int* __restrict__ b, int n) {
    int i = blockIdx.x * blockDim.x + threadIdx.x;
    if (i < n) { a[i] = 0; b[i] = 0; }
}

// ---------------- pass 1: coarse bucket histogram (LDS-privatized) ----------------
__global__ __launch_bounds__(256) void bhist_kernel(const int* __restrict__ col, int* __restrict__ ghist) {
    __shared__ int h[NBKT];
    int t = threadIdx.x;
    for (int i = t; i < NBKT; i += 256) h[i] = 0;
    __syncthreads();
    int e0 = blockIdx.x * SCHUNK;
    int e1 = min(e0 + SCHUNK, EE);
    for (int e = e0 + t; e < e1; e += 256) atomicAdd(&h[col[e] >> 7], 1);
    __syncthreads();
    for (int i = t; i < NBKT; i += 256) {
        int v = h[i];
        if (v) atomicAdd(&ghist[i], v);
    }
}

// ---------------- pass 2: bucket base scan (single block) ----------------
__global__ __launch_bounds__(1024) void bscan_kernel(const int* __restrict__ ghist,
                                                     int* __restrict__ gbase, int* __restrict__ gcur) {
    __shared__ int s[1024];
    int t = threadIdx.x;
    int v = (t < NBKT) ? ghist[t] : 0;
    s[t] = v;
    __syncthreads();
    for (int d = 1; d < 1024; d <<= 1) {
        int a = (t >= d) ? s[t - d] : 0;
        __syncthreads();
        s[t] += a;
        __syncthreads();
    }
    int excl = s[t] - v;
    if (t <= NBKT) gbase[t] = excl;   // gbase[NBKT] = EE
    if (t < NBKT) gcur[t] = excl;
}

// ---------------- pass 3: binned scatter into bucket-sorted order ----------------
// per-block: LDS hist -> one global reservation atomic per touched bucket -> LDS-cursor ranks.
__global__ __launch_bounds__(256) void bscatter_kernel(const int* __restrict__ row, const int* __restrict__ col,
                                                       int* __restrict__ gcur, int2* __restrict__ packed) {
    __shared__ int h[NBKT];
    __shared__ int basec[NBKT];
    int t = threadIdx.x;
    for (int i = t; i < NBKT; i += 256) h[i] = 0;
    __syncthreads();
    int e0 = blockIdx.x * SCHUNK;
    int e1 = min(e0 + SCHUNK, EE);
    for (int e = e0 + t; e < e1; e += 256) atomicAdd(&h[col[e] >> 7], 1);
    __syncthreads();
    for (int i = t; i < NBKT; i += 256) {
        int v = h[i];
        basec[i] = v ? atomicAdd(&gcur[i], v) : 0;
    }
    __syncthreads();
    for (int i = t; i < NBKT; i += 256) h[i] = 0;
    __syncthreads();
    for (int e = e0 + t; e < e1; e += 256) {
        int c = col[e];
        int b = c >> 7;
        int p = basec[b] + atomicAdd(&h[b], 1);
        packed[p] = make_int2(row[e], c);
    }
}

// ---------------- pass 4: per-bucket CSR finalize (also emits cnt/off) ----------------
__global__ __launch_bounds__(256) void bfinal_kernel(const int2* __restrict__ packed, const int* __restrict__ gbase,
                                                     int* __restrict__ cnt, int* __restrict__ off,
                                                     int* __restrict__ csr) {
    __shared__ int h[128];
    __shared__ int sc[128];
    int b = blockIdx.x, t = threadIdx.x;
    int s0 = gbase[b], s1 = gbase[b + 1];
    if (t < 128) h[t] = 0;
    __syncthreads();
    for (int e = s0 + t; e < s1; e += 256) atomicAdd(&h[packed[e].y & 127], 1);
    __syncthreads();
    int hv = 0;
    if (t < 128) { hv = h[t]; sc[t] = hv; }
    __syncthreads();
    for (int d = 1; d < 128; d <<= 1) {
        int a = (t >= d && t < 128) ? sc[t - d] : 0;
        __syncthreads();
        if (t < 128) sc[t] += a;
        __syncthreads();
    }
    int excl = 0;
    if (t < 128) excl = sc[t] - hv;
    __syncthreads();
    if (t < 128) h[t] = excl;      // reuse as per-node cursor
    int node = b * 128 + t;
    if (t < 128 && node < NN) {
        cnt[node] = hv;
        off[node] = s0 + excl;
    }
    __syncthreads();
    for (int e = s0 + t; e < s1; e += 256) {
        int2 pc = packed[e];
        int rk = atomicAdd(&h[pc.y & 127], 1);
        csr[s0 + rk] = pc.x;
    }
}

// ---------------- dinv (3 configs) ----------------
__global__ __launch_bounds__(256) void dinv_kernel(const int* __restrict__ cp, const int* __restrict__ cs,
                                                   float* __restrict__ dp1, float* __restrict__ dp2,
                                                   float* __restrict__ ds2, int n) {
    int i = blockIdx.x * blockDim.x + threadIdx.x;
    if (i < n) {
        float fp = (float)cp[i];
        float fs = (float)cs[i];
        dp1[i] = rsqrtf(fp + 0.3f);
        dp2[i] = rsqrtf(fp + 0.5f);
        ds2[i] = rsqrtf(fs + 0.5f);
    }
}

// ---------------- W -> bf16 B-fragment-major conversion ----------------
__global__ __launch_bounds__(256) void wconv_kernel(const float* __restrict__ w1,
                                                    const float* __restrict__ w2,
                                                    uint4* __restrict__ wfrag) {
    int u = blockIdx.x * 256 + threadIdx.x;   // 0..2047
    if (u >= 2048) return;
    int lane = u & 63;
    int ks   = (u >> 6) & 3;
    int ct   = u >> 8;
    int c    = ct * 16 + (lane & 15);
    int k0   = ks * 32 + (lane >> 4) * 8;
    const float* src = (c < 64) ? (w1 + c * 128 + k0) : (w2 + (c - 64) * 128 + k0);
    float4 p0 = ((const float4*)src)[0];
    float4 p1 = ((const float4*)src)[1];
    uint4 q;
    q.x = pack2bf(p0.x, p0.y);
    q.y = pack2bf(p0.z, p0.w);
    q.z = pack2bf(p1.x, p1.y);
    q.w = pack2bf(p1.z, p1.w);
    wfrag[u] = q;
}

// ---------------- MFMA dual GEMM + g-table epilogue ----------------
__global__ __launch_bounds__(256) void gemm_kernel(const float* __restrict__ x,
                                                   const uint4* __restrict__ wfrag,
                                                   const float* __restrict__ b1, const float* __restrict__ b2,
                                                   const float* __restrict__ dp1, const float* __restrict__ dp2,
                                                   const float* __restrict__ ds2,
                                                   float* __restrict__ h1, float* __restrict__ h2,
                                                   ushort* __restrict__ g1, ushort* __restrict__ g2s,
                                                   ushort* __restrict__ g2p) {
    __shared__ uint4 alds[32 * 68];   // 34 KB, 17-unit swizzle
    int t = threadIdx.x;
    int lane = t & 63;
    int wave = t >> 6;
    int row0 = blockIdx.x * 128;

    FragU bfrag[2][4];
#pragma unroll
    for (int ctl = 0; ctl < 2; ctl++)
#pragma unroll
        for (int ks = 0; ks < 4; ks++)
            bfrag[ctl][ks].u = wfrag[((wave * 2 + ctl) * 4 + ks) * 64 + lane];

    {
        int m = t >> 4;
        int g = t & 15;
        const float4* xv = (const float4*)x;
#pragma unroll
        for (int s = 0; s < 8; s++) {
            int r = row0 + s * 16 + m;
            int rc = (r < NN) ? r : (NN - 1);
            float4 p0 = xv[rc * 32 + g * 2];
            float4 p1 = xv[rc * 32 + g * 2 + 1];
            uint4 q;
            q.x = pack2bf(p0.x, p0.y);
            q.y = pack2bf(p0.z, p0.w);
            q.z = pack2bf(p1.x, p1.y);
            q.w = pack2bf(p1.z, p1.w);
            alds[(s * 4 + (g >> 2)) * 68 + (g & 3) * 17 + m] = q;
        }
    }
    __syncthreads();

    int cA = (wave * 2 + 0) * 16 + (lane & 15);
    int cB = cA + 16;
    float biasA = (wave < 2) ? b1[cA] : b2[cA - 64];
    float biasB = (wave < 2) ? b1[cB] : b2[cB - 64];
    float4a acc[8][2];
#pragma unroll
    for (int rt = 0; rt < 8; rt++) {
        acc[rt][0] = float4a{biasA, biasA, biasA, biasA};
        acc[rt][1] = float4a{biasB, biasB, biasB, biasB};
    }

    int quad = lane >> 4;
    int asig = quad * 17 + (lane & 15);
#pragma unroll
    for (int rt = 0; rt < 8; rt++) {
        FragU af[4];
#pragma unroll
        for (int ks = 0; ks < 4; ks++)
            af[ks].u = alds[(rt * 4 + ks) * 68 + asig];
#pragma unroll
        for (int ks = 0; ks < 4; ks++) {
            acc[rt][0] = __builtin_amdgcn_mfma_f32_16x16x32_bf16(af[ks].s, bfrag[0][ks].s, acc[rt][0], 0, 0, 0);
            acc[rt][1] = __builtin_amdgcn_mfma_f32_16x16x32_bf16(af[ks].s, bfrag[1][ks].s, acc[rt][1], 0, 0, 0);
        }
    }

#pragma unroll
    for (int rt = 0; rt < 8; rt++) {
        int rb = row0 + rt * 16 + quad * 4;
#pragma unroll
        for (int ctl = 0; ctl < 2; ctl++) {
            int c = (wave * 2 + ctl) * 16 + (lane & 15);
#pragma unroll
            for (int reg = 0; reg < 4; reg++) {
                int r = rb + reg;
                if (r >= NN) continue;
                float v = acc[rt][ctl][reg];
                if (wave < 2) {
                    h1[r * 64 + c] = v;
                    g1[r * 64 + c] = f2bf(v * dp1[r]);
                } else {
                    int cc = c - 64;
                    h2[r * 64 + cc]  = v;
                    g2s[r * 64 + cc] = f2bf(v * ds2[r]);
                    g2p[r * 64 + cc] = f2bf(v * dp2[r]);
                }
            }
        }
    }
}

// ---------------- SpMM pass, bf16 source-scaled gather table ----------------
__global__ __launch_bounds__(256) void spmm_kernel(const float* __restrict__ hin,
                                                   const uint* __restrict__ gin,
                                                   const int* __restrict__ off,
                                                   const int* __restrict__ cnt,
                                                   const int* __restrict__ csr,
                                                   const float* __restrict__ dinv,
                                                   float eps,
                                                   const float* __restrict__ extra,
                                                   float* __restrict__ hout,
                                                   ushort* __restrict__ gout,
                                                   const float* __restrict__ dnext) {
    int tid = blockIdx.x * blockDim.x + threadIdx.x;
    int node = tid >> 3;
    if (node >= NN) return;
    int fc = tid & 7;
    const uint4* gv = (const uint4*)gin;

    int o = off[node];
    int c = cnt[node];
    float dc = dinv[node];
    float selfc = (1.0f - eps) + eps * dc * dc;

    float s0f = 0, s1f = 0, s2f = 0, s3f = 0, s4f = 0, s5f = 0, s6f = 0, s7f = 0;

    int e = 0;
    for (; e + 3 < c; e += 4) {
        int n0 = csr[o + e];
        int n1 = csr[o + e + 1];
        int n2 = csr[o + e + 2];
        int n3 = csr[o + e + 3];
        uint4 q0 = gv[n0 * 8 + fc];
        uint4 q1 = gv[n1 * 8 + fc];
        uint4 q2 = gv[n2 * 8 + fc];
        uint4 q3 = gv[n3 * 8 + fc];
        s0f += (bf2f_lo(q0.x) + bf2f_lo(q1.x)) + (bf2f_lo(q2.x) + bf2f_lo(q3.x));
        s1f += (bf2f_hi(q0.x) + bf2f_hi(q1.x)) + (bf2f_hi(q2.x) + bf2f_hi(q3.x));
        s2f += (bf2f_lo(q0.y) + bf2f_lo(q1.y)) + (bf2f_lo(q2.y) + bf2f_lo(q3.y));
        s3f += (bf2f_hi(q0.y) + bf2f_hi(q1.y)) + (bf2f_hi(q2.y) + bf2f_hi(q3.y));
        s4f += (bf2f_lo(q0.z) + bf2f_lo(q1.z)) + (bf2f_lo(q2.z) + bf2f_lo(q3.z));
        s5f += (bf2f_hi(q0.z) + bf2f_hi(q1.z)) + (bf2f_hi(q2.z) + bf2f_hi(q3.z));
        s6f += (bf2f_lo(q0.w) + bf2f_lo(q1.w)) + (bf2f_lo(q2.w) + bf2f_lo(q3.w));
        s7f += (bf2f_hi(q0.w) + bf2f_hi(q1.w)) + (bf2f_hi(q2.w) + bf2f_hi(q3.w));
    }
    for (; e < c; e++) {
        int n0 = csr[o + e];
        uint4 q0 = gv[n0 * 8 + fc];
        s0f += bf2f_lo(q0.x);
        s1f += bf2f_hi(q0.x);
        s2f += bf2f_lo(q0.y);
        s3f += bf2f_hi(q0.y);
        s4f += bf2f_lo(q0.z);
        s5f += bf2f_hi(q0.z);
        s6f += bf2f_lo(q0.w);
        s7f += bf2f_hi(q0.w);
    }

    const float4* hv = (const float4*)hin;
    float4 ha = hv[node * 16 + fc * 2];
    float4 hb = hv[node * 16 + fc * 2 + 1];
    float o0 = selfc * ha.x + dc * s0f;
    float o1 = selfc * ha.y + dc * s1f;
    float o2 = selfc * ha.z + dc * s2f;
    float o3 = selfc * ha.w + dc * s3f;
    float o4 = selfc * hb.x + dc * s4f;
    float o5 = selfc * hb.y + dc * s5f;
    float o6 = selfc * hb.z + dc * s6f;
    float o7 = selfc * hb.w + dc * s7f;

    if (extra) {
        const float4* ev = (const float4*)extra;
        float4 ea = ev[node * 16 + fc * 2];
        float4 eb = ev[node * 16 + fc * 2 + 1];
        o0 += ea.x; o1 += ea.y; o2 += ea.z; o3 += ea.w;
        o4 += eb.x; o5 += eb.y; o6 += eb.z; o7 += eb.w;
    }

    float4* ho = (float4*)hout;
    ho[node * 16 + fc * 2]     = make_float4(o0, o1, o2, o3);
    ho[node * 16 + fc * 2 + 1] = make_float4(o4, o5, o6, o7);

    if (gout) {
        float dn = dnext[node];
        uint4 gq;
        gq.x = pack2bf(o0 * dn, o1 * dn);
        gq.y = pack2bf(o2 * dn, o3 * dn);
        gq.z = pack2bf(o4 * dn, o5 * dn);
        gq.w = pack2bf(o6 * dn, o7 * dn);
        ((uint4*)gout)[node * 8 + fc] = gq;
    }
}

extern "C" void kernel_launch(void* const* d_in, const int* in_sizes, int n_in,
                              void* d_out, int out_size, void* d_ws, size_t ws_size,
                              hipStream_t stream) {
    const float* x  = (const float*)d_in[0];
    const int* pri  = (const int*)d_in[1];
    const int* sup  = (const int*)d_in[2];
    const float* w1 = (const float*)d_in[3];
    const float* b1 = (const float*)d_in[4];
    const float* w2 = (const float*)d_in[5];
    const float* b2 = (const float*)d_in[6];
    float* out = (float*)d_out;

    char* ws = (char*)d_ws;
    auto alloc = [&](size_t bytes) -> char* {
        char* p = ws;
        ws += (bytes + 255) & ~(size_t)255;
        return p;
    };
    int* cnt_p  = (int*)alloc(NN * 4);
    int* cnt_s  = (int*)alloc(NN * 4);
    int* off_p  = (int*)alloc(NN * 4);
    int* off_s  = (int*)alloc(NN * 4);
    int* ghist_p = (int*)alloc((NBKT + 1) * 4);
    int* ghist_s = (int*)alloc((NBKT + 1) * 4);
    int* gbase_p = (int*)alloc((NBKT + 1) * 4);
    int* gbase_s = (int*)alloc((NBKT + 1) * 4);
    int* gcur_p  = (int*)alloc((NBKT + 1) * 4);
    int* gcur_s  = (int*)alloc((NBKT + 1) * 4);
    int* csr_p  = (int*)alloc((size_t)EE * 4);
    int* csr_s  = (int*)alloc((size_t)EE * 4);
    float* dv_p1 = (float*)alloc(NN * 4);
    float* dv_p2 = (float*)alloc(NN * 4);
    float* dv_s2 = (float*)alloc(NN * 4);
    uint4* wfrag = (uint4*)alloc(2048 * 16);
    float* h1 = (float*)alloc((size_t)NN * HH * 4);   // also tB later
    float* h2 = (float*)alloc((size_t)NN * HH * 4);
    float* tA = (float*)alloc((size_t)NN * HH * 4);
    ushort* g1  = (ushort*)alloc((size_t)NN * HH * 2);  // also gS later
    ushort* gt  = (ushort*)alloc((size_t)NN * HH * 2);  // also gP later
    ushort* g2s = (ushort*)alloc((size_t)NN * HH * 2);
    ushort* g2p = (ushort*)alloc((size_t)NN * HH * 2);
    float* tB = h1;
    ushort* gS = g1;
    ushort* gP = gt;
    // packed edge buffers alias later-written tensors (CSR build fully precedes gemm)
    int2* packed_p = (int2*)tA;    // 12.8 MB <= 25.6 MB
    int2* packed_s = (int2*)g2s;   // 12.8 MB == 12.8 MB

    const int* pri_row = pri;
    const int* pri_col = pri + EE;
    const int* sup_row = sup;
    const int* sup_col = sup + EE;

    const int NB_N = (NN + 255) / 256;
    const int NB_CH = (EE + SCHUNK - 1) / SCHUNK;   // 196
    const int NB_SPMM = (NN * 8 + 255) / 256;       // 3125
    const int NB_GEMM = (NN + 127) / 128;           // 782

    // --- CSR build: two-level counting sort, both edge sets ---
    zero2_kernel<<<(NBKT + 255) / 256, 256, 0, stream>>>(ghist_p, ghist_s, NBKT);
    bhist_kernel<<<NB_CH, 256, 0, stream>>>(pri_col, ghist_p);
    bhist_kernel<<<NB_CH, 256, 0, stream>>>(sup_col, ghist_s);
    bscan_kernel<<<1, 1024, 0, stream>>>(ghist_p, gbase_p, gcur_p);
    bscan_kernel<<<1, 1024, 0, stream>>>(ghist_s, gbase_s, gcur_s);
    bscatter_kernel<<<NB_CH, 256, 0, stream>>>(pri_row, pri_col, gcur_p, packed_p);
    bscatter_kernel<<<NB_CH, 256, 0, stream>>>(sup_row, sup_col, gcur_s, packed_s);
    bfinal_kernel<<<NBKT, 256, 0, stream>>>(packed_p, gbase_p, cnt_p, off_p, csr_p);
    bfinal_kernel<<<NBKT, 256, 0, stream>>>(packed_s, gbase_s, cnt_s, off_s, csr_s);

    dinv_kernel<<<NB_N, 256, 0, stream>>>(cnt_p, cnt_s, dv_p1, dv_p2, dv_s2, NN);

    // --- W conversion + MFMA dual GEMM ---
    wconv_kernel<<<8, 256, 0, stream>>>(w1, w2, wfrag);
    gemm_kernel<<<NB_GEMM, 256, 0, stream>>>(x, wfrag, b1, b2, dv_p1, dv_p2, dv_s2,
                                             h1, h2, g1, g2s, g2p);

    // --- z1: two hops on pri, eps=0.3 ---
    spmm_kernel<<<NB_SPMM, 256, 0, stream>>>(h1, (const uint*)g1, off_p, cnt_p, csr_p, dv_p1, 0.3f,
                                             nullptr, tA, gt, dv_p1);
    spmm_kernel<<<NB_SPMM, 256, 0, stream>>>(tA, (const uint*)gt, off_p, cnt_p, csr_p, dv_p1, 0.3f,
                                             nullptr, out, nullptr, nullptr);

    // --- z2 branch A: two hops on sup, eps=0.5 ---
    spmm_kernel<<<NB_SPMM, 256, 0, stream>>>(h2, (const uint*)g2s, off_s, cnt_s, csr_s, dv_s2, 0.5f,
                                             nullptr, tA, gS, dv_s2);
    spmm_kernel<<<NB_SPMM, 256, 0, stream>>>(tA, (const uint*)gS, off_s, cnt_s, csr_s, dv_s2, 0.5f,
                                             nullptr, tB, nullptr, nullptr);

    // --- z2 branch B: two hops on pri, eps=0.5, fuse +tB ---
    spmm_kernel<<<NB_SPMM, 256, 0, stream>>>(h2, (const uint*)g2p, off_p, cnt_p, csr_p, dv_p2, 0.5f,
                                             nullptr, tA, gP, dv_p2);
    spmm_kernel<<<NB_SPMM, 256, 0, stream>>>(tA, (const uint*)gP, off_p, cnt_p, csr_p, dv_p2, 0.5f,
                                             tB, out + (size_t)NN * HH, nullptr, nullptr);
}

// Round 5
// 453.103 us; speedup vs baseline: 2.2196x; 1.1455x over previous
//
#include <hip/hip_runtime.h>

#define NN 100000
#define EE 1600000
#define FIN 128
#define HH 64
#define NBKT 782          // ceil(NN/128) coarse buckets
#define SCHUNK 4096       // edges per block in hist/scatter passes
#define NCH 391           // ceil(EE/SCHUNK)

typedef unsigned int uint;
typedef unsigned short ushort;
typedef __attribute__((ext_vector_type(8))) short short8;
typedef __attribute__((ext_vector_type(4))) float float4a;

union FragU { uint4 u; short8 s; };

static __device__ __forceinline__ ushort f2bf(float f) {
    uint u = __float_as_uint(f);
    uint r = (u + 0x7fffu + ((u >> 16) & 1u)) >> 16;   // RNE
    return (ushort)r;
}
static __device__ __forceinline__ uint pack2bf(float a, float b) {
    return (uint)f2bf(a) | ((uint)f2bf(b) << 16);
}
static __device__ __forceinline__ float bf2f_lo(uint u) {
    return __uint_as_float(u << 16);
}
static __device__ __forceinline__ float bf2f_hi(uint u) {
    return __uint_as_float(u & 0xffff0000u);
}
static __device__ __forceinline__ void qadd(float* a, uint4 q) {
    a[0] += bf2f_lo(q.x); a[1] += bf2f_hi(q.x);
    a[2] += bf2f_lo(q.y); a[3] += bf2f_hi(q.y);
    a[4] += bf2f_lo(q.z); a[5] += bf2f_hi(q.z);
    a[6] += bf2f_lo(q.w); a[7] += bf2f_hi(q.w);
}

// ---------------- zero two int arrays ----------------
__global__ __launch_bounds__(256) void zero2_kernel(int* __restrict__ a, int* __restrict__ b, int n) {
    int i = blockIdx.x * blockDim.x + threadIdx.x;
    if (i < n) { a[i] = 0; b[i] = 0; }
}

// ---------------- pass 1: coarse bucket histogram, both sets ----------------
__global__ __launch_bounds__(256) void bhist_kernel(const int* __restrict__ pri, const int* __restrict__ sup,
                                                    int* __restrict__ ghp, int* __restrict__ ghs) {
    __shared__ int h[NBKT];
    int bid = blockIdx.x;
    int set = (bid >= NCH) ? 1 : 0;
    int chunk = bid - set * NCH;
    const int* col = (set ? sup : pri) + EE;
    int* gh = set ? ghs : ghp;
    int t = threadIdx.x;
    for (int i = t; i < NBKT; i += 256) h[i] = 0;
    __syncthreads();
    int e0 = chunk * SCHUNK;
    int e1 = min(e0 + SCHUNK, EE);
    for (int e = e0 + t; e < e1; e += 256) atomicAdd(&h[col[e] >> 7], 1);
    __syncthreads();
    for (int i = t; i < NBKT; i += 256) {
        int v = h[i];
        if (v) atomicAdd(&gh[i], v);
    }
}

// ---------------- pass 2: bucket base scan, block 0 = pri, block 1 = sup ----------------
__global__ __launch_bounds__(1024) void bscan_kernel(const int* __restrict__ ghp, int* __restrict__ gbp, int* __restrict__ gcp,
                                                     const int* __restrict__ ghs, int* __restrict__ gbs, int* __restrict__ gcs) {
    __shared__ int s[1024];
    const int* gh = blockIdx.x ? ghs : ghp;
    int* gb = blockIdx.x ? gbs : gbp;
    int* gc = blockIdx.x ? gcs : gcp;
    int t = threadIdx.x;
    int v = (t < NBKT) ? gh[t] : 0;
    s[t] = v;
    __syncthreads();
    for (int d = 1; d < 1024; d <<= 1) {
        int a = (t >= d) ? s[t - d] : 0;
        __syncthreads();
        s[t] += a;
        __syncthreads();
    }
    int excl = s[t] - v;
    if (t <= NBKT) gb[t] = excl;   // gb[NBKT] = EE
    if (t < NBKT) gc[t] = excl;
}

// ---------------- pass 3: binned scatter (packed uint: row | fine<<17), both sets ----------------
__global__ __launch_bounds__(256) void bscatter_kernel(const int* __restrict__ pri, const int* __restrict__ sup,
                                                       int* __restrict__ gcp, int* __restrict__ gcs,
                                                       uint* __restrict__ pkp, uint* __restrict__ pks) {
    __shared__ int h[NBKT];
    __shared__ int basec[NBKT];
    int bid = blockIdx.x;
    int set = (bid >= NCH) ? 1 : 0;
    int chunk = bid - set * NCH;
    const int* row = set ? sup : pri;
    const int* col = row + EE;
    int* gcur = set ? gcs : gcp;
    uint* packed = set ? pks : pkp;
    int t = threadIdx.x;
    for (int i = t; i < NBKT; i += 256) h[i] = 0;
    __syncthreads();
    int e0 = chunk * SCHUNK;
    int e1 = min(e0 + SCHUNK, EE);
    for (int e = e0 + t; e < e1; e += 256) atomicAdd(&h[col[e] >> 7], 1);
    __syncthreads();
    for (int i = t; i < NBKT; i += 256) {
        int v = h[i];
        basec[i] = v ? atomicAdd(&gcur[i], v) : 0;
    }
    __syncthreads();
    for (int i = t; i < NBKT; i += 256) h[i] = 0;
    __syncthreads();
    for (int e = e0 + t; e < e1; e += 256) {
        int c = col[e];
        int b = c >> 7;
        int p = basec[b] + atomicAdd(&h[b], 1);
        packed[p] = (uint)row[e] | ((uint)(c & 127) << 17);
    }
}

// ---------------- pass 4: per-bucket CSR finalize + cnt/off, both sets ----------------
__global__ __launch_bounds__(256) void bfinal_kernel(const uint* __restrict__ pkp, const int* __restrict__ gbp,
                                                     int* __restrict__ cntp, int* __restrict__ offp, int* __restrict__ csrp,
                                                     const uint* __restrict__ pks, const int* __restrict__ gbs,
                                                     int* __restrict__ cnts, int* __restrict__ offs, int* __restrict__ csrs) {
    __shared__ int h[128];
    __shared__ int sc[128];
    int bid = blockIdx.x;
    int set = (bid >= NBKT) ? 1 : 0;
    int b = bid - set * NBKT;
    const uint* packed = set ? pks : pkp;
    const int* gbase = set ? gbs : gbp;
    int* cnt = set ? cnts : cntp;
    int* off = set ? offs : offp;
    int* csr = set ? csrs : csrp;
    int t = threadIdx.x;
    int s0 = gbase[b], s1 = gbase[b + 1];
    if (t < 128) h[t] = 0;
    __syncthreads();
    for (int e = s0 + t; e < s1; e += 256) atomicAdd(&h[(packed[e] >> 17) & 127], 1);
    __syncthreads();
    int hv = 0;
    if (t < 128) { hv = h[t]; sc[t] = hv; }
    __syncthreads();
    for (int d = 1; d < 128; d <<= 1) {
        int a = (t >= d && t < 128) ? sc[t - d] : 0;
        __syncthreads();
        if (t < 128) sc[t] += a;
        __syncthreads();
    }
    int excl = 0;
    if (t < 128) excl = sc[t] - hv;
    __syncthreads();
    if (t < 128) h[t] = excl;      // reuse as per-node cursor
    int node = b * 128 + t;
    if (t < 128 && node < NN) {
        cnt[node] = hv;
        off[node] = s0 + excl;
    }
    __syncthreads();
    for (int e = s0 + t; e < s1; e += 256) {
        uint pc = packed[e];
        int rk = atomicAdd(&h[(pc >> 17) & 127], 1);
        csr[s0 + rk] = (int)(pc & 0x1FFFFu);
    }
}

// ---------------- dinv (3 configs) ----------------
__global__ __launch_bounds__(256) void dinv_kernel(const int* __restrict__ cp, const int* __restrict__ cs,
                                                   float* __restrict__ dp1, float* __restrict__ dp2,
                                                   float* __restrict__ ds2, int n) {
    int i = blockIdx.x * blockDim.x + threadIdx.x;
    if (i < n) {
        float fp = (float)cp[i];
        float fs = (float)cs[i];
        dp1[i] = rsqrtf(fp + 0.3f);
        dp2[i] = rsqrtf(fp + 0.5f);
        ds2[i] = rsqrtf(fs + 0.5f);
    }
}

// ---------------- W -> bf16 B-fragment-major conversion ----------------
__global__ __launch_bounds__(256) void wconv_kernel(const float* __restrict__ w1,
                                                    const float* __restrict__ w2,
                                                    uint4* __restrict__ wfrag) {
    int u = blockIdx.x * 256 + threadIdx.x;   // 0..2047
    if (u >= 2048) return;
    int lane = u & 63;
    int ks   = (u >> 6) & 3;
    int ct   = u >> 8;
    int c    = ct * 16 + (lane & 15);
    int k0   = ks * 32 + (lane >> 4) * 8;
    const float* src = (c < 64) ? (w1 + c * 128 + k0) : (w2 + (c - 64) * 128 + k0);
    float4 p0 = ((const float4*)src)[0];
    float4 p1 = ((const float4*)src)[1];
    uint4 q;
    q.x = pack2bf(p0.x, p0.y);
    q.y = pack2bf(p0.z, p0.w);
    q.z = pack2bf(p1.x, p1.y);
    q.w = pack2bf(p1.z, p1.w);
    wfrag[u] = q;
}

// ---------------- MFMA dual GEMM + g-table epilogue ----------------
__global__ __launch_bounds__(256) void gemm_kernel(const float* __restrict__ x,
                                                   const uint4* __restrict__ wfrag,
                                                   const float* __restrict__ b1, const float* __restrict__ b2,
                                                   const float* __restrict__ dp1, const float* __restrict__ dp2,
                                                   const float* __restrict__ ds2,
                                                   float* __restrict__ h1, float* __restrict__ h2,
                                                   ushort* __restrict__ g1, ushort* __restrict__ g2s,
                                                   ushort* __restrict__ g2p) {
    __shared__ uint4 alds[32 * 68];   // 34 KB, 17-unit swizzle
    int t = threadIdx.x;
    int lane = t & 63;
    int wave = t >> 6;
    int row0 = blockIdx.x * 128;

    FragU bfrag[2][4];
#pragma unroll
    for (int ctl = 0; ctl < 2; ctl++)
#pragma unroll
        for (int ks = 0; ks < 4; ks++)
            bfrag[ctl][ks].u = wfrag[((wave * 2 + ctl) * 4 + ks) * 64 + lane];

    {
        int m = t >> 4;
        int g = t & 15;
        const float4* xv = (const float4*)x;
#pragma unroll
        for (int s = 0; s < 8; s++) {
            int r = row0 + s * 16 + m;
            int rc = (r < NN) ? r : (NN - 1);
            float4 p0 = xv[rc * 32 + g * 2];
            float4 p1 = xv[rc * 32 + g * 2 + 1];
            uint4 q;
            q.x = pack2bf(p0.x, p0.y);
            q.y = pack2bf(p0.z, p0.w);
            q.z = pack2bf(p1.x, p1.y);
            q.w = pack2bf(p1.z, p1.w);
            alds[(s * 4 + (g >> 2)) * 68 + (g & 3) * 17 + m] = q;
        }
    }
    __syncthreads();

    int cA = (wave * 2 + 0) * 16 + (lane & 15);
    int cB = cA + 16;
    float biasA = (wave < 2) ? b1[cA] : b2[cA - 64];
    float biasB = (wave < 2) ? b1[cB] : b2[cB - 64];
    float4a acc[8][2];
#pragma unroll
    for (int rt = 0; rt < 8; rt++) {
        acc[rt][0] = float4a{biasA, biasA, biasA, biasA};
        acc[rt][1] = float4a{biasB, biasB, biasB, biasB};
    }

    int quad = lane >> 4;
    int asig = quad * 17 + (lane & 15);
#pragma unroll
    for (int rt = 0; rt < 8; rt++) {
        FragU af[4];
#pragma unroll
        for (int ks = 0; ks < 4; ks++)
            af[ks].u = alds[(rt * 4 + ks) * 68 + asig];
#pragma unroll
        for (int ks = 0; ks < 4; ks++) {
            acc[rt][0] = __builtin_amdgcn_mfma_f32_16x16x32_bf16(af[ks].s, bfrag[0][ks].s, acc[rt][0], 0, 0, 0);
            acc[rt][1] = __builtin_amdgcn_mfma_f32_16x16x32_bf16(af[ks].s, bfrag[1][ks].s, acc[rt][1], 0, 0, 0);
        }
    }

#pragma unroll
    for (int rt = 0; rt < 8; rt++) {
        int rb = row0 + rt * 16 + quad * 4;
#pragma unroll
        for (int ctl = 0; ctl < 2; ctl++) {
            int c = (wave * 2 + ctl) * 16 + (lane & 15);
#pragma unroll
            for (int reg = 0; reg < 4; reg++) {
                int r = rb + reg;
                if (r >= NN) continue;
                float v = acc[rt][ctl][reg];
                if (wave < 2) {
                    h1[r * 64 + c] = v;
                    g1[r * 64 + c] = f2bf(v * dp1[r]);
                } else {
                    int cc = c - 64;
                    h2[r * 64 + cc]  = v;
                    g2s[r * 64 + cc] = f2bf(v * ds2[r]);
                    g2p[r * 64 + cc] = f2bf(v * dp2[r]);
                }
            }
        }
    }
}

// ---------------- fused hop 1: all three branches in one pass ----------------
// pri graph: z1 (g1, eps .3) and z2-pri (g2p, eps .5); sup graph: z2-sup (g2s, eps .5).
// h1/h2 updated in place (only the owning thread reads its own h row); tAs = z2 half of d_out.
__global__ __launch_bounds__(256) void spmm1_kernel(float* h1io, float* h2io, float* tAs,
        const uint* __restrict__ g1, const uint* __restrict__ g2p, const uint* __restrict__ g2s,
        ushort* __restrict__ gt1, ushort* __restrict__ gtp, ushort* __restrict__ gts,
        const int* __restrict__ off_p, const int* __restrict__ cnt_p, const int* __restrict__ csr_p,
        const int* __restrict__ off_s, const int* __restrict__ cnt_s, const int* __restrict__ csr_s,
        const float* __restrict__ dvp1, const float* __restrict__ dvp2, const float* __restrict__ dvs2) {
    int tid = blockIdx.x * 256 + threadIdx.x;
    int node = tid >> 3;
    if (node >= NN) return;
    int fc = tid & 7;
    const uint4* g1v = (const uint4*)g1;
    const uint4* gpv = (const uint4*)g2p;
    const uint4* gsv = (const uint4*)g2s;

    float a1[8] = {0, 0, 0, 0, 0, 0, 0, 0};
    float ap[8] = {0, 0, 0, 0, 0, 0, 0, 0};
    float as[8] = {0, 0, 0, 0, 0, 0, 0, 0};

    {   // pri edges: two tables per edge
        int o = off_p[node], c = cnt_p[node];
        int e = 0;
        for (; e + 1 < c; e += 2) {
            int s0 = csr_p[o + e], s1 = csr_p[o + e + 1];
            uint4 qa0 = g1v[s0 * 8 + fc];
            uint4 qb0 = gpv[s0 * 8 + fc];
            uint4 qa1 = g1v[s1 * 8 + fc];
            uint4 qb1 = gpv[s1 * 8 + fc];
            qadd(a1, qa0); qadd(ap, qb0);
            qadd(a1, qa1); qadd(ap, qb1);
        }
        if (e < c) {
            int s0 = csr_p[o + e];
            qadd(a1, g1v[s0 * 8 + fc]);
            qadd(ap, gpv[s0 * 8 + fc]);
        }
    }
    {   // sup edges
        int o = off_s[node], c = cnt_s[node];
        int e = 0;
        for (; e + 3 < c; e += 4) {
            int s0 = csr_s[o + e], s1 = csr_s[o + e + 1];
            int s2 = csr_s[o + e + 2], s3 = csr_s[o + e + 3];
            uint4 q0 = gsv[s0 * 8 + fc];
            uint4 q1 = gsv[s1 * 8 + fc];
            uint4 q2 = gsv[s2 * 8 + fc];
            uint4 q3 = gsv[s3 * 8 + fc];
            qadd(as, q0); qadd(as, q1); qadd(as, q2); qadd(as, q3);
        }
        for (; e < c; e++) qadd(as, gsv[csr_s[o + e] * 8 + fc]);
    }

    float dp1 = dvp1[node], dp2 = dvp2[node], ds2 = dvs2[node];
    float sp1 = 0.7f + 0.3f * dp1 * dp1;
    float sp2 = 0.5f + 0.5f * dp2 * dp2;
    float ss2 = 0.5f + 0.5f * ds2 * ds2;

    float4* h1v = (float4*)h1io;
    float4* h2v = (float4*)h2io;
    float4 h1a = h1v[node * 16 + fc * 2], h1b = h1v[node * 16 + fc * 2 + 1];
    float4 h2a = h2v[node * 16 + fc * 2], h2b = h2v[node * 16 + fc * 2 + 1];
    float h1f[8] = {h1a.x, h1a.y, h1a.z, h1a.w, h1b.x, h1b.y, h1b.z, h1b.w};
    float h2f[8] = {h2a.x, h2a.y, h2a.z, h2a.w, h2b.x, h2b.y, h2b.z, h2b.w};

    float o1[8], op[8], os[8];
#pragma unroll
    for (int i = 0; i < 8; i++) {
        o1[i] = sp1 * h1f[i] + dp1 * a1[i];
        op[i] = sp2 * h2f[i] + dp2 * ap[i];
        os[i] = ss2 * h2f[i] + ds2 * as[i];
    }

    h1v[node * 16 + fc * 2]     = make_float4(o1[0], o1[1], o1[2], o1[3]);
    h1v[node * 16 + fc * 2 + 1] = make_float4(o1[4], o1[5], o1[6], o1[7]);
    h2v[node * 16 + fc * 2]     = make_float4(op[0], op[1], op[2], op[3]);
    h2v[node * 16 + fc * 2 + 1] = make_float4(op[4], op[5], op[6], op[7]);
    float4* tsv = (float4*)tAs;
    tsv[node * 16 + fc * 2]     = make_float4(os[0], os[1], os[2], os[3]);
    tsv[node * 16 + fc * 2 + 1] = make_float4(os[4], os[5], os[6], os[7]);

    uint4 q;
    q.x = pack2bf(o1[0] * dp1, o1[1] * dp1);
    q.y = pack2bf(o1[2] * dp1, o1[3] * dp1);
    q.z = pack2bf(o1[4] * dp1, o1[5] * dp1);
    q.w = pack2bf(o1[6] * dp1, o1[7] * dp1);
    ((uint4*)gt1)[node * 8 + fc] = q;
    q.x = pack2bf(op[0] * dp2, op[1] * dp2);
    q.y = pack2bf(op[2] * dp2, op[3] * dp2);
    q.z = pack2bf(op[4] * dp2, op[5] * dp2);
    q.w = pack2bf(op[6] * dp2, op[7] * dp2);
    ((uint4*)gtp)[node * 8 + fc] = q;
    q.x = pack2bf(os[0] * ds2, os[1] * ds2);
    q.y = pack2bf(os[2] * ds2, os[3] * ds2);
    q.z = pack2bf(os[4] * ds2, os[5] * ds2);
    q.w = pack2bf(os[6] * ds2, os[7] * ds2);
    ((uint4*)gts)[node * 8 + fc] = q;
}

// ---------------- fused hop 2: final outputs, z2 = pri + sup fused ----------------
__global__ __launch_bounds__(256) void spmm2_kernel(const float* __restrict__ tA1, const float* __restrict__ tAp,
        float* tAsio,   // z2 half of d_out: read (sup hop-1 result), then overwritten with final z2
        const uint* __restrict__ gt1, const uint* __restrict__ gtp, const uint* __restrict__ gts,
        const int* __restrict__ off_p, const int* __restrict__ cnt_p, const int* __restrict__ csr_p,
        const int* __restrict__ off_s, const int* __restrict__ cnt_s, const int* __restrict__ csr_s,
        const float* __restrict__ dvp1, const float* __restrict__ dvp2, const float* __restrict__ dvs2,
        float* __restrict__ out1) {
    int tid = blockIdx.x * 256 + threadIdx.x;
    int node = tid >> 3;
    if (node >= NN) return;
    int fc = tid & 7;
    const uint4* g1v = (const uint4*)gt1;
    const uint4* gpv = (const uint4*)gtp;
    const uint4* gsv = (const uint4*)gts;

    float a1[8] = {0, 0, 0, 0, 0, 0, 0, 0};
    float ap[8] = {0, 0, 0, 0, 0, 0, 0, 0};
    float as[8] = {0, 0, 0, 0, 0, 0, 0, 0};

    {
        int o = off_p[node], c = cnt_p[node];
        int e = 0;
        for (; e + 1 < c; e += 2) {
            int s0 = csr_p[o + e], s1 = csr_p[o + e + 1];
            uint4 qa0 = g1v[s0 * 8 + fc];
            uint4 qb0 = gpv[s0 * 8 + fc];
            uint4 qa1 = g1v[s1 * 8 + fc];
            uint4 qb1 = gpv[s1 * 8 + fc];
            qadd(a1, qa0); qadd(ap, qb0);
            qadd(a1, qa1); qadd(ap, qb1);
        }
        if (e < c) {
            int s0 = csr_p[o + e];
            qadd(a1, g1v[s0 * 8 + fc]);
            qadd(ap, gpv[s0 * 8 + fc]);
        }
    }
    {
        int o = off_s[node], c = cnt_s[node];
        int e = 0;
        for (; e + 3 < c; e += 4) {
            int s0 = csr_s[o + e], s1 = csr_s[o + e + 1];
            int s2 = csr_s[o + e + 2], s3 = csr_s[o + e + 3];
            uint4 q0 = gsv[s0 * 8 + fc];
            uint4 q1 = gsv[s1 * 8 + fc];
            uint4 q2 = gsv[s2 * 8 + fc];
            uint4 q3 = gsv[s3 * 8 + fc];
            qadd(as, q0); qadd(as, q1); qadd(as, q2); qadd(as, q3);
        }
        for (; e < c; e++) qadd(as, gsv[csr_s[o + e] * 8 + fc]);
    }

    float dp1 = dvp1[node], dp2 = dvp2[node], ds2 = dvs2[node];
    float sp1 = 0.7f + 0.3f * dp1 * dp1;
    float sp2 = 0.5f + 0.5f * dp2 * dp2;
    float ss2 = 0.5f + 0.5f * ds2 * ds2;

    const float4* t1v = (const float4*)tA1;
    const float4* tpv = (const float4*)tAp;
    float4* tsv = (float4*)tAsio;
    float4 t1a = t1v[node * 16 + fc * 2], t1b = t1v[node * 16 + fc * 2 + 1];
    float4 tpa = tpv[node * 16 + fc * 2], tpb = tpv[node * 16 + fc * 2 + 1];
    float4 tsa = tsv[node * 16 + fc * 2], tsb = tsv[node * 16 + fc * 2 + 1];
    float t1f[8] = {t1a.x, t1a.y, t1a.z, t1a.w, t1b.x, t1b.y, t1b.z, t1b.w};
    float tpf[8] = {tpa.x, tpa.y, tpa.z, tpa.w, tpb.x, tpb.y, tpb.z, tpb.w};
    float tsf[8] = {tsa.x, tsa.y, tsa.z, tsa.w, tsb.x, tsb.y, tsb.z, tsb.w};

    float oz1[8], oz2[8];
#pragma unroll
    for (int i = 0; i < 8; i++) {
        oz1[i] = sp1 * t1f[i] + dp1 * a1[i];
        oz2[i] = (sp2 * tpf[i] + dp2 * ap[i]) + (ss2 * tsf[i] + ds2 * as[i]);
    }

    float4* o1v = (float4*)out1;
    o1v[node * 16 + fc * 2]     = make_float4(oz1[0], oz1[1], oz1[2], oz1[3]);
    o1v[node * 16 + fc * 2 + 1] = make_float4(oz1[4], oz1[5], oz1[6], oz1[7]);
    tsv[node * 16 + fc * 2]     = make_float4(oz2[0], oz2[1], oz2[2], oz2[3]);
    tsv[node * 16 + fc * 2 + 1] = make_float4(oz2[4], oz2[5], oz2[6], oz2[7]);
}

extern "C" void kernel_launch(void* const* d_in, const int* in_sizes, int n_in,
                              void* d_out, int out_size, void* d_ws, size_t ws_size,
                              hipStream_t stream) {
    const float* x  = (const float*)d_in[0];
    const int* pri  = (const int*)d_in[1];
    const int* sup  = (const int*)d_in[2];
    const float* w1 = (const float*)d_in[3];
    const float* b1 = (const float*)d_in[4];
    const float* w2 = (const float*)d_in[5];
    const float* b2 = (const float*)d_in[6];
    float* out = (float*)d_out;

    char* ws = (char*)d_ws;
    auto alloc = [&](size_t bytes) -> char* {
        char* p = ws;
        ws += (bytes + 255) & ~(size_t)255;
        return p;
    };
    int* cnt_p  = (int*)alloc(NN * 4);
    int* cnt_s  = (int*)alloc(NN * 4);
    int* off_p  = (int*)alloc(NN * 4);
    int* off_s  = (int*)alloc(NN * 4);
    int* ghist_p = (int*)alloc((NBKT + 1) * 4);
    int* ghist_s = (int*)alloc((NBKT + 1) * 4);
    int* gbase_p = (int*)alloc((NBKT + 1) * 4);
    int* gbase_s = (int*)alloc((NBKT + 1) * 4);
    int* gcur_p  = (int*)alloc((NBKT + 1) * 4);
    int* gcur_s  = (int*)alloc((NBKT + 1) * 4);
    int* csr_p  = (int*)alloc((size_t)EE * 4);
    int* csr_s  = (int*)alloc((size_t)EE * 4);
    float* dv_p1 = (float*)alloc(NN * 4);
    float* dv_p2 = (float*)alloc(NN * 4);
    float* dv_s2 = (float*)alloc(NN * 4);
    uint4* wfrag = (uint4*)alloc(2048 * 16);
    float* h1 = (float*)alloc((size_t)NN * HH * 4);
    float* h2 = (float*)alloc((size_t)NN * HH * 4);
    ushort* g1  = (ushort*)alloc((size_t)NN * HH * 2);
    ushort* g2s = (ushort*)alloc((size_t)NN * HH * 2);
    ushort* g2p = (ushort*)alloc((size_t)NN * HH * 2);
    ushort* gt1 = (ushort*)alloc((size_t)NN * HH * 2);
    ushort* gtp = (ushort*)alloc((size_t)NN * HH * 2);
    ushort* gts = (ushort*)alloc((size_t)NN * HH * 2);
    // packed buffers alias gt tables (consumed by bfinal before spmm1 writes gt)
    uint* packed_p = (uint*)gt1;   // 6.4 MB <= 12.8 MB
    uint* packed_s = (uint*)gtp;
    float* tAs = out + (size_t)NN * HH;   // z2 half of d_out as hop-1 sup scratch

    const int NB_N = (NN + 255) / 256;
    const int NB_SPMM = (NN * 8 + 255) / 256;       // 3125
    const int NB_GEMM = (NN + 127) / 128;           // 782

    // --- CSR build (two-level counting sort, both sets per launch) ---
    zero2_kernel<<<(NBKT + 255) / 256, 256, 0, stream>>>(ghist_p, ghist_s, NBKT);
    bhist_kernel<<<2 * NCH, 256, 0, stream>>>(pri, sup, ghist_p, ghist_s);
    bscan_kernel<<<2, 1024, 0, stream>>>(ghist_p, gbase_p, gcur_p, ghist_s, gbase_s, gcur_s);
    bscatter_kernel<<<2 * NCH, 256, 0, stream>>>(pri, sup, gcur_p, gcur_s, packed_p, packed_s);
    bfinal_kernel<<<2 * NBKT, 256, 0, stream>>>(packed_p, gbase_p, cnt_p, off_p, csr_p,
                                                packed_s, gbase_s, cnt_s, off_s, csr_s);

    dinv_kernel<<<NB_N, 256, 0, stream>>>(cnt_p, cnt_s, dv_p1, dv_p2, dv_s2, NN);

    // --- W conversion + MFMA dual GEMM ---
    wconv_kernel<<<8, 256, 0, stream>>>(w1, w2, wfrag);
    gemm_kernel<<<NB_GEMM, 256, 0, stream>>>(x, wfrag, b1, b2, dv_p1, dv_p2, dv_s2,
                                             h1, h2, g1, g2s, g2p);

    // --- fused hop 1 (3 branches) + fused hop 2 (final z1, z2) ---
    spmm1_kernel<<<NB_SPMM, 256, 0, stream>>>(h1, h2, tAs,
                                              (const uint*)g1, (const uint*)g2p, (const uint*)g2s,
                                              gt1, gtp, gts,
                                              off_p, cnt_p, csr_p, off_s, cnt_s, csr_s,
                                              dv_p1, dv_p2, dv_s2);
    spmm2_kernel<<<NB_SPMM, 256, 0, stream>>>(h1, h2, tAs,
                                              (const uint*)gt1, (const uint*)gtp, (const uint*)gts,
                                              off_p, cnt_p, csr_p, off_s, cnt_s, csr_s,
                                              dv_p1, dv_p2, dv_s2, out);
}

// Round 7
// 416.607 us; speedup vs baseline: 2.4140x; 1.0876x over previous
//
#include <hip/hip_runtime.h>

#define NN 100000
#define EE 1600000
#define FIN 128
#define HH 64
#define NBKT 782          // ceil(NN/128) coarse buckets
#define SCHUNK 4096       // edges per block in hist/scatter passes
#define NCH 391           // ceil(EE/SCHUNK)

typedef unsigned int uint;
typedef unsigned short ushort;
typedef __attribute__((ext_vector_type(8))) short short8;
typedef __attribute__((ext_vector_type(4))) float float4a;
typedef __attribute__((ext_vector_type(4))) uint uint4a;

union FragU { uint4 u; short8 s; };

static __device__ __forceinline__ ushort f2bf(float f) {
    uint u = __float_as_uint(f);
    uint r = (u + 0x7fffu + ((u >> 16) & 1u)) >> 16;   // RNE
    return (ushort)r;
}
static __device__ __forceinline__ uint pack2bf(float a, float b) {
    return (uint)f2bf(a) | ((uint)f2bf(b) << 16);
}
static __device__ __forceinline__ float bf2f_lo(uint u) {
    return __uint_as_float(u << 16);
}
static __device__ __forceinline__ float bf2f_hi(uint u) {
    return __uint_as_float(u & 0xffff0000u);
}
static __device__ __forceinline__ void qadd(float* a, uint4 q) {
    a[0] += bf2f_lo(q.x); a[1] += bf2f_hi(q.x);
    a[2] += bf2f_lo(q.y); a[3] += bf2f_hi(q.y);
    a[4] += bf2f_lo(q.z); a[5] += bf2f_hi(q.z);
    a[6] += bf2f_lo(q.w); a[7] += bf2f_hi(q.w);
}
static __device__ __forceinline__ void qset(float* a, uint4 q) {
    a[0] = bf2f_lo(q.x); a[1] = bf2f_hi(q.x);
    a[2] = bf2f_lo(q.y); a[3] = bf2f_hi(q.y);
    a[4] = bf2f_lo(q.z); a[5] = bf2f_hi(q.z);
    a[6] = bf2f_lo(q.w); a[7] = bf2f_hi(q.w);
}

// ---------------- zero two int arrays ----------------
__global__ __launch_bounds__(256) void zero2_kernel(int* __restrict__ a, int* __restrict__ b, int n) {
    int i = blockIdx.x * blockDim.x + threadIdx.x;
    if (i < n) { a[i] = 0; b[i] = 0; }
}

// ---------------- pass 1: coarse bucket histogram, both sets, int4 reads ----------------
__global__ __launch_bounds__(256) void bhist_kernel(const int* __restrict__ pri, const int* __restrict__ sup,
                                                    int* __restrict__ ghp, int* __restrict__ ghs) {
    __shared__ int h[NBKT];
    int bid = blockIdx.x;
    int set = (bid >= NCH) ? 1 : 0;
    int chunk = bid - set * NCH;
    const int* col = (set ? sup : pri) + EE;
    int* gh = set ? ghs : ghp;
    int t = threadIdx.x;
    for (int i = t; i < NBKT; i += 256) h[i] = 0;
    __syncthreads();
    int e0 = chunk * SCHUNK;
    int e1 = min(e0 + SCHUNK, EE);
    for (int e = e0 + t * 4; e < e1; e += 1024) {
        int4 c4 = *(const int4*)(col + e);
        atomicAdd(&h[c4.x >> 7], 1);
        atomicAdd(&h[c4.y >> 7], 1);
        atomicAdd(&h[c4.z >> 7], 1);
        atomicAdd(&h[c4.w >> 7], 1);
    }
    __syncthreads();
    for (int i = t; i < NBKT; i += 256) {
        int v = h[i];
        if (v) atomicAdd(&gh[i], v);
    }
}

// ---------------- pass 2: bucket base scan, block 0 = pri, block 1 = sup ----------------
__global__ __launch_bounds__(1024) void bscan_kernel(const int* __restrict__ ghp, int* __restrict__ gbp, int* __restrict__ gcp,
                                                     const int* __restrict__ ghs, int* __restrict__ gbs, int* __restrict__ gcs) {
    __shared__ int s[1024];
    const int* gh = blockIdx.x ? ghs : ghp;
    int* gb = blockIdx.x ? gbs : gbp;
    int* gc = blockIdx.x ? gcs : gcp;
    int t = threadIdx.x;
    int v = (t < NBKT) ? gh[t] : 0;
    s[t] = v;
    __syncthreads();
    for (int d = 1; d < 1024; d <<= 1) {
        int a = (t >= d) ? s[t - d] : 0;
        __syncthreads();
        s[t] += a;
        __syncthreads();
    }
    int excl = s[t] - v;
    if (t <= NBKT) gb[t] = excl;   // gb[NBKT] = EE
    if (t < NBKT) gc[t] = excl;
}

// ---------------- pass 3: binned scatter (packed uint: row | fine<<17), both sets ----------------
__global__ __launch_bounds__(256) void bscatter_kernel(const int* __restrict__ pri, const int* __restrict__ sup,
                                                       int* __restrict__ gcp, int* __restrict__ gcs,
                                                       uint* __restrict__ pkp, uint* __restrict__ pks) {
    __shared__ int h[NBKT];
    __shared__ int basec[NBKT];
    int bid = blockIdx.x;
    int set = (bid >= NCH) ? 1 : 0;
    int chunk = bid - set * NCH;
    const int* row = set ? sup : pri;
    const int* col = row + EE;
    int* gcur = set ? gcs : gcp;
    uint* packed = set ? pks : pkp;
    int t = threadIdx.x;
    for (int i = t; i < NBKT; i += 256) h[i] = 0;
    __syncthreads();
    int e0 = chunk * SCHUNK;
    int e1 = min(e0 + SCHUNK, EE);
    for (int e = e0 + t * 4; e < e1; e += 1024) {
        int4 c4 = *(const int4*)(col + e);
        atomicAdd(&h[c4.x >> 7], 1);
        atomicAdd(&h[c4.y >> 7], 1);
        atomicAdd(&h[c4.z >> 7], 1);
        atomicAdd(&h[c4.w >> 7], 1);
    }
    __syncthreads();
    for (int i = t; i < NBKT; i += 256) {
        int v = h[i];
        basec[i] = v ? atomicAdd(&gcur[i], v) : 0;
    }
    __syncthreads();
    for (int i = t; i < NBKT; i += 256) h[i] = 0;
    __syncthreads();
    for (int e = e0 + t * 4; e < e1; e += 1024) {
        int4 c4 = *(const int4*)(col + e);
        int4 r4 = *(const int4*)(row + e);
        int b0 = c4.x >> 7, b1 = c4.y >> 7, b2 = c4.z >> 7, b3 = c4.w >> 7;
        int p0 = basec[b0] + atomicAdd(&h[b0], 1);
        int p1 = basec[b1] + atomicAdd(&h[b1], 1);
        int p2 = basec[b2] + atomicAdd(&h[b2], 1);
        int p3 = basec[b3] + atomicAdd(&h[b3], 1);
        packed[p0] = (uint)r4.x | ((uint)(c4.x & 127) << 17);
        packed[p1] = (uint)r4.y | ((uint)(c4.y & 127) << 17);
        packed[p2] = (uint)r4.z | ((uint)(c4.z & 127) << 17);
        packed[p3] = (uint)r4.w | ((uint)(c4.w & 127) << 17);
    }
}

// ---------------- pass 4: per-bucket CSR finalize + cnt/off, both sets ----------------
__global__ __launch_bounds__(256) void bfinal_kernel(const uint* __restrict__ pkp, const int* __restrict__ gbp,
                                                     int* __restrict__ cntp, int* __restrict__ offp, int* __restrict__ csrp,
                                                     const uint* __restrict__ pks, const int* __restrict__ gbs,
                                                     int* __restrict__ cnts, int* __restrict__ offs, int* __restrict__ csrs) {
    __shared__ int h[128];
    __shared__ int sc[128];
    int bid = blockIdx.x;
    int set = (bid >= NBKT) ? 1 : 0;
    int b = bid - set * NBKT;
    const uint* packed = set ? pks : pkp;
    const int* gbase = set ? gbs : gbp;
    int* cnt = set ? cnts : cntp;
    int* off = set ? offs : offp;
    int* csr = set ? csrs : csrp;
    int t = threadIdx.x;
    int s0 = gbase[b], s1 = gbase[b + 1];
    if (t < 128) h[t] = 0;
    __syncthreads();
    for (int e = s0 + t; e < s1; e += 256) atomicAdd(&h[(packed[e] >> 17) & 127], 1);
    __syncthreads();
    int hv = 0;
    if (t < 128) { hv = h[t]; sc[t] = hv; }
    __syncthreads();
    for (int d = 1; d < 128; d <<= 1) {
        int a = (t >= d && t < 128) ? sc[t - d] : 0;
        __syncthreads();
        if (t < 128) sc[t] += a;
        __syncthreads();
    }
    int excl = 0;
    if (t < 128) excl = sc[t] - hv;
    __syncthreads();
    if (t < 128) h[t] = excl;      // reuse as per-node cursor
    int node = b * 128 + t;
    if (t < 128 && node < NN) {
        cnt[node] = hv;
        off[node] = s0 + excl;
    }
    __syncthreads();
    for (int e = s0 + t; e < s1; e += 256) {
        uint pc = packed[e];
        int rk = atomicAdd(&h[(pc >> 17) & 127], 1);
        csr[s0 + rk] = (int)(pc & 0x1FFFFu);
    }
}

// ---------------- dinv (3 configs) ----------------
__global__ __launch_bounds__(256) void dinv_kernel(const int* __restrict__ cp, const int* __restrict__ cs,
                                                   float* __restrict__ dp1, float* __restrict__ dp2,
                                                   float* __restrict__ ds2, int n) {
    int i = blockIdx.x * blockDim.x + threadIdx.x;
    if (i < n) {
        float fp = (float)cp[i];
        float fs = (float)cs[i];
        dp1[i] = rsqrtf(fp + 0.3f);
        dp2[i] = rsqrtf(fp + 0.5f);
        ds2[i] = rsqrtf(fs + 0.5f);
    }
}

// ---------------- W -> bf16 B-fragment-major conversion ----------------
__global__ __launch_bounds__(256) void wconv_kernel(const float* __restrict__ w1,
                                                    const float* __restrict__ w2,
                                                    uint4* __restrict__ wfrag) {
    int u = blockIdx.x * 256 + threadIdx.x;   // 0..2047
    if (u >= 2048) return;
    int lane = u & 63;
    int ks   = (u >> 6) & 3;
    int ct   = u >> 8;
    int c    = ct * 16 + (lane & 15);
    int k0   = ks * 32 + (lane >> 4) * 8;
    const float* src = (c < 64) ? (w1 + c * 128 + k0) : (w2 + (c - 64) * 128 + k0);
    float4 p0 = ((const float4*)src)[0];
    float4 p1 = ((const float4*)src)[1];
    uint4 q;
    q.x = pack2bf(p0.x, p0.y);
    q.y = pack2bf(p0.z, p0.w);
    q.z = pack2bf(p1.x, p1.y);
    q.w = pack2bf(p1.z, p1.w);
    wfrag[u] = q;
}

// ---------------- MFMA dual GEMM -> bf16 g-tables only (no fp32 h) ----------------
__global__ __launch_bounds__(256) void gemm_kernel(const float* __restrict__ x,
                                                   const uint4* __restrict__ wfrag,
                                                   const float* __restrict__ b1, const float* __restrict__ b2,
                                                   const float* __restrict__ dp1, const float* __restrict__ dp2,
                                                   const float* __restrict__ ds2,
                                                   ushort* __restrict__ g1, ushort* __restrict__ g2s,
                                                   ushort* __restrict__ g2p) {
    __shared__ uint4 alds[32 * 68];   // 34 KB, 17-unit swizzle
    int t = threadIdx.x;
    int lane = t & 63;
    int wave = t >> 6;
    int row0 = blockIdx.x * 128;

    FragU bfrag[2][4];
#pragma unroll
    for (int ctl = 0; ctl < 2; ctl++)
#pragma unroll
        for (int ks = 0; ks < 4; ks++)
            bfrag[ctl][ks].u = wfrag[((wave * 2 + ctl) * 4 + ks) * 64 + lane];

    {
        int m = t >> 4;
        int g = t & 15;
        const float4* xv = (const float4*)x;
#pragma unroll
        for (int s = 0; s < 8; s++) {
            int r = row0 + s * 16 + m;
            int rc = (r < NN) ? r : (NN - 1);
            float4 p0 = xv[rc * 32 + g * 2];
            float4 p1 = xv[rc * 32 + g * 2 + 1];
            uint4 q;
            q.x = pack2bf(p0.x, p0.y);
            q.y = pack2bf(p0.z, p0.w);
            q.z = pack2bf(p1.x, p1.y);
            q.w = pack2bf(p1.z, p1.w);
            alds[(s * 4 + (g >> 2)) * 68 + (g & 3) * 17 + m] = q;
        }
    }
    __syncthreads();

    int cA = (wave * 2 + 0) * 16 + (lane & 15);
    int cB = cA + 16;
    float biasA = (wave < 2) ? b1[cA] : b2[cA - 64];
    float biasB = (wave < 2) ? b1[cB] : b2[cB - 64];
    float4a acc[8][2];
#pragma unroll
    for (int rt = 0; rt < 8; rt++) {
        acc[rt][0] = float4a{biasA, biasA, biasA, biasA};
        acc[rt][1] = float4a{biasB, biasB, biasB, biasB};
    }

    int quad = lane >> 4;
    int asig = quad * 17 + (lane & 15);
#pragma unroll
    for (int rt = 0; rt < 8; rt++) {
        FragU af[4];
#pragma unroll
        for (int ks = 0; ks < 4; ks++)
            af[ks].u = alds[(rt * 4 + ks) * 68 + asig];
#pragma unroll
        for (int ks = 0; ks < 4; ks++) {
            acc[rt][0] = __builtin_amdgcn_mfma_f32_16x16x32_bf16(af[ks].s, bfrag[0][ks].s, acc[rt][0], 0, 0, 0);
            acc[rt][1] = __builtin_amdgcn_mfma_f32_16x16x32_bf16(af[ks].s, bfrag[1][ks].s, acc[rt][1], 0, 0, 0);
        }
    }

#pragma unroll
    for (int rt = 0; rt < 8; rt++) {
        int rb = row0 + rt * 16 + quad * 4;
#pragma unroll
        for (int ctl = 0; ctl < 2; ctl++) {
            int c = (wave * 2 + ctl) * 16 + (lane & 15);
#pragma unroll
            for (int reg = 0; reg < 4; reg++) {
                int r = rb + reg;
                if (r >= NN) continue;
                float v = acc[rt][ctl][reg];
                if (wave < 2) {
                    g1[r * 64 + c] = f2bf(v * dp1[r]);
                } else {
                    int cc = c - 64;
                    g2s[r * 64 + cc] = f2bf(v * ds2[r]);
                    g2p[r * 64 + cc] = f2bf(v * dp2[r]);
                }
            }
        }
    }
}

// ---------------- fused hop 1: 3 branches, g-only dataflow ----------------
// Self terms reconstructed from own g rows (h = g_own / dinv). Writes only next-hop tables.
__global__ __launch_bounds__(256) void spmm1_kernel(
        const uint* __restrict__ g1, const uint* __restrict__ g2p, const uint* __restrict__ g2s,
        ushort* __restrict__ gt1, ushort* __restrict__ gtp, ushort* __restrict__ gts,
        const int* __restrict__ off_p, const int* __restrict__ cnt_p, const int* __restrict__ csr_p,
        const int* __restrict__ off_s, const int* __restrict__ cnt_s, const int* __restrict__ csr_s,
        const float* __restrict__ dvp1, const float* __restrict__ dvp2, const float* __restrict__ dvs2) {
    int tid = blockIdx.x * 256 + threadIdx.x;
    int node = tid >> 3;
    if (node >= NN) return;
    int fc = tid & 7;
    const uint4* g1v = (const uint4*)g1;
    const uint4* gpv = (const uint4*)g2p;
    const uint4* gsv = (const uint4*)g2s;

    float a1[8] = {0, 0, 0, 0, 0, 0, 0, 0};
    float ap[8] = {0, 0, 0, 0, 0, 0, 0, 0};
    float as[8] = {0, 0, 0, 0, 0, 0, 0, 0};

    {   // pri edges: two tables per edge
        int o = off_p[node], c = cnt_p[node];
        int e = 0;
        for (; e + 1 < c; e += 2) {
            int s0 = csr_p[o + e], s1 = csr_p[o + e + 1];
            uint4 qa0 = g1v[s0 * 8 + fc];
            uint4 qb0 = gpv[s0 * 8 + fc];
            uint4 qa1 = g1v[s1 * 8 + fc];
            uint4 qb1 = gpv[s1 * 8 + fc];
            qadd(a1, qa0); qadd(ap, qb0);
            qadd(a1, qa1); qadd(ap, qb1);
        }
        if (e < c) {
            int s0 = csr_p[o + e];
            qadd(a1, g1v[s0 * 8 + fc]);
            qadd(ap, gpv[s0 * 8 + fc]);
        }
    }
    {   // sup edges
        int o = off_s[node], c = cnt_s[node];
        int e = 0;
        for (; e + 3 < c; e += 4) {
            int s0 = csr_s[o + e], s1 = csr_s[o + e + 1];
            int s2 = csr_s[o + e + 2], s3 = csr_s[o + e + 3];
            uint4 q0 = gsv[s0 * 8 + fc];
            uint4 q1 = gsv[s1 * 8 + fc];
            uint4 q2 = gsv[s2 * 8 + fc];
            uint4 q3 = gsv[s3 * 8 + fc];
            qadd(as, q0); qadd(as, q1); qadd(as, q2); qadd(as, q3);
        }
        for (; e < c; e++) qadd(as, gsv[csr_s[o + e] * 8 + fc]);
    }

    float dp1 = dvp1[node], dp2 = dvp2[node], ds2 = dvs2[node];
    float sp1 = 0.7f + 0.3f * dp1 * dp1;
    float sp2 = 0.5f + 0.5f * dp2 * dp2;
    float ss2 = 0.5f + 0.5f * ds2 * ds2;
    // self-term coefficients applied directly to own table rows: h = g_own/d
    float c1 = sp1 / dp1;
    float cp = sp2 / dp2;
    float cs = ss2 / dp2;   // z2s self uses h2 = g2p_own/dp2

    float t1f[8], tpf[8];
    qset(t1f, g1v[node * 8 + fc]);
    qset(tpf, gpv[node * 8 + fc]);

    float o1[8], op[8], os[8];
#pragma unroll
    for (int i = 0; i < 8; i++) {
        o1[i] = c1 * t1f[i] + dp1 * a1[i];
        op[i] = cp * tpf[i] + dp2 * ap[i];
        os[i] = cs * tpf[i] + ds2 * as[i];
    }

    uint4a q;
    q.x = pack2bf(o1[0] * dp1, o1[1] * dp1);
    q.y = pack2bf(o1[2] * dp1, o1[3] * dp1);
    q.z = pack2bf(o1[4] * dp1, o1[5] * dp1);
    q.w = pack2bf(o1[6] * dp1, o1[7] * dp1);
    __builtin_nontemporal_store(q, ((uint4a*)gt1) + node * 8 + fc);
    q.x = pack2bf(op[0] * dp2, op[1] * dp2);
    q.y = pack2bf(op[2] * dp2, op[3] * dp2);
    q.z = pack2bf(op[4] * dp2, op[5] * dp2);
    q.w = pack2bf(op[6] * dp2, op[7] * dp2);
    __builtin_nontemporal_store(q, ((uint4a*)gtp) + node * 8 + fc);
    q.x = pack2bf(os[0] * ds2, os[1] * ds2);
    q.y = pack2bf(os[2] * ds2, os[3] * ds2);
    q.z = pack2bf(os[4] * ds2, os[5] * ds2);
    q.w = pack2bf(os[6] * ds2, os[7] * ds2);
    __builtin_nontemporal_store(q, ((uint4a*)gts) + node * 8 + fc);
}

// ---------------- fused hop 2: final outputs, z2 = pri + sup fused ----------------
__global__ __launch_bounds__(256) void spmm2_kernel(
        const uint* __restrict__ gt1, const uint* __restrict__ gtp, const uint* __restrict__ gts,
        const int* __restrict__ off_p, const int* __restrict__ cnt_p, const int* __restrict__ csr_p,
        const int* __restrict__ off_s, const int* __restrict__ cnt_s, const int* __restrict__ csr_s,
        const float* __restrict__ dvp1, const float* __restrict__ dvp2, const float* __restrict__ dvs2,
        float* __restrict__ out1, float* __restrict__ out2) {
    int tid = blockIdx.x * 256 + threadIdx.x;
    int node = tid >> 3;
    if (node >= NN) return;
    int fc = tid & 7;
    const uint4* g1v = (const uint4*)gt1;
    const uint4* gpv = (const uint4*)gtp;
    const uint4* gsv = (const uint4*)gts;

    float a1[8] = {0, 0, 0, 0, 0, 0, 0, 0};
    float ap[8] = {0, 0, 0, 0, 0, 0, 0, 0};
    float as[8] = {0, 0, 0, 0, 0, 0, 0, 0};

    {
        int o = off_p[node], c = cnt_p[node];
        int e = 0;
        for (; e + 1 < c; e += 2) {
            int s0 = csr_p[o + e], s1 = csr_p[o + e + 1];
            uint4 qa0 = g1v[s0 * 8 + fc];
            uint4 qb0 = gpv[s0 * 8 + fc];
            uint4 qa1 = g1v[s1 * 8 + fc];
            uint4 qb1 = gpv[s1 * 8 + fc];
            qadd(a1, qa0); qadd(ap, qb0);
            qadd(a1, qa1); qadd(ap, qb1);
        }
        if (e < c) {
            int s0 = csr_p[o + e];
            qadd(a1, g1v[s0 * 8 + fc]);
            qadd(ap, gpv[s0 * 8 + fc]);
        }
    }
    {
        int o = off_s[node], c = cnt_s[node];
        int e = 0;
        for (; e + 3 < c; e += 4) {
            int s0 = csr_s[o + e], s1 = csr_s[o + e + 1];
            int s2 = csr_s[o + e + 2], s3 = csr_s[o + e + 3];
            uint4 q0 = gsv[s0 * 8 + fc];
            uint4 q1 = gsv[s1 * 8 + fc];
            uint4 q2 = gsv[s2 * 8 + fc];
            uint4 q3 = gsv[s3 * 8 + fc];
            qadd(as, q0); qadd(as, q1); qadd(as, q2); qadd(as, q3);
        }
        for (; e < c; e++) qadd(as, gsv[csr_s[o + e] * 8 + fc]);
    }

    float dp1 = dvp1[node], dp2 = dvp2[node], ds2 = dvs2[node];
    float sp1 = 0.7f + 0.3f * dp1 * dp1;
    float sp2 = 0.5f + 0.5f * dp2 * dp2;
    float ss2 = 0.5f + 0.5f * ds2 * ds2;
    float c1 = sp1 / dp1;
    float cp = sp2 / dp2;
    float cs = ss2 / ds2;

    float t1f[8], tpf[8], tsf[8];
    qset(t1f, g1v[node * 8 + fc]);
    qset(tpf, gpv[node * 8 + fc]);
    qset(tsf, gsv[node * 8 + fc]);

    float oz1[8], oz2[8];
#pragma unroll
    for (int i = 0; i < 8; i++) {
        oz1[i] = c1 * t1f[i] + dp1 * a1[i];
        oz2[i] = (cp * tpf[i] + dp2 * ap[i]) + (cs * tsf[i] + ds2 * as[i]);
    }

    float4a* o1v = (float4a*)out1;
    float4a* o2v = (float4a*)out2;
    float4a v;
    v.x = oz1[0]; v.y = oz1[1]; v.z = oz1[2]; v.w = oz1[3];
    __builtin_nontemporal_store(v, o1v + node * 16 + fc * 2);
    v.x = oz1[4]; v.y = oz1[5]; v.z = oz1[6]; v.w = oz1[7];
    __builtin_nontemporal_store(v, o1v + node * 16 + fc * 2 + 1);
    v.x = oz2[0]; v.y = oz2[1]; v.z = oz2[2]; v.w = oz2[3];
    __builtin_nontemporal_store(v, o2v + node * 16 + fc * 2);
    v.x = oz2[4]; v.y = oz2[5]; v.z = oz2[6]; v.w = oz2[7];
    __builtin_nontemporal_store(v, o2v + node * 16 + fc * 2 + 1);
}

extern "C" void kernel_launch(void* const* d_in, const int* in_sizes, int n_in,
                              void* d_out, int out_size, void* d_ws, size_t ws_size,
                              hipStream_t stream) {
    const float* x  = (const float*)d_in[0];
    const int* pri  = (const int*)d_in[1];
    const int* sup  = (const int*)d_in[2];
    const float* w1 = (const float*)d_in[3];
    const float* b1 = (const float*)d_in[4];
    const float* w2 = (const float*)d_in[5];
    const float* b2 = (const float*)d_in[6];
    float* out = (float*)d_out;

    char* ws = (char*)d_ws;
    auto alloc = [&](size_t bytes) -> char* {
        char* p = ws;
        ws += (bytes + 255) & ~(size_t)255;
        return p;
    };
    int* cnt_p  = (int*)alloc(NN * 4);
    int* cnt_s  = (int*)alloc(NN * 4);
    int* off_p  = (int*)alloc(NN * 4);
    int* off_s  = (int*)alloc(NN * 4);
    int* ghist_p = (int*)alloc((NBKT + 1) * 4);
    int* ghist_s = (int*)alloc((NBKT + 1) * 4);
    int* gbase_p = (int*)alloc((NBKT + 1) * 4);
    int* gbase_s = (int*)alloc((NBKT + 1) * 4);
    int* gcur_p  = (int*)alloc((NBKT + 1) * 4);
    int* gcur_s  = (int*)alloc((NBKT + 1) * 4);
    int* csr_p  = (int*)alloc((size_t)EE * 4);
    int* csr_s  = (int*)alloc((size_t)EE * 4);
    float* dv_p1 = (float*)alloc(NN * 4);
    float* dv_p2 = (float*)alloc(NN * 4);
    float* dv_s2 = (float*)alloc(NN * 4);
    uint4* wfrag = (uint4*)alloc(2048 * 16);
    ushort* g1  = (ushort*)alloc((size_t)NN * HH * 2);
    ushort* g2s = (ushort*)alloc((size_t)NN * HH * 2);
    ushort* g2p = (ushort*)alloc((size_t)NN * HH * 2);
    ushort* gt1 = (ushort*)alloc((size_t)NN * HH * 2);
    ushort* gtp = (ushort*)alloc((size_t)NN * HH * 2);
    ushort* gts = (ushort*)alloc((size_t)NN * HH * 2);
    // packed buffers alias gt tables (consumed by bfinal before spmm1 writes gt)
    uint* packed_p = (uint*)gt1;   // 6.4 MB <= 12.8 MB
    uint* packed_s = (uint*)gtp;

    const int NB_N = (NN + 255) / 256;
    const int NB_SPMM = (NN * 8 + 255) / 256;       // 3125
    const int NB_GEMM = (NN + 127) / 128;           // 782

    // --- CSR build (two-level counting sort, both sets per launch) ---
    zero2_kernel<<<(NBKT + 255) / 256, 256, 0, stream>>>(ghist_p, ghist_s, NBKT);
    bhist_kernel<<<2 * NCH, 256, 0, stream>>>(pri, sup, ghist_p, ghist_s);
    bscan_kernel<<<2, 1024, 0, stream>>>(ghist_p, gbase_p, gcur_p, ghist_s, gbase_s, gcur_s);
    bscatter_kernel<<<2 * NCH, 256, 0, stream>>>(pri, sup, gcur_p, gcur_s, packed_p, packed_s);
    bfinal_kernel<<<2 * NBKT, 256, 0, stream>>>(packed_p, gbase_p, cnt_p, off_p, csr_p,
                                                packed_s, gbase_s, cnt_s, off_s, csr_s);

    dinv_kernel<<<NB_N, 256, 0, stream>>>(cnt_p, cnt_s, dv_p1, dv_p2, dv_s2, NN);

    // --- W conversion + MFMA dual GEMM (g-tables only) ---
    wconv_kernel<<<8, 256, 0, stream>>>(w1, w2, wfrag);
    gemm_kernel<<<NB_GEMM, 256, 0, stream>>>(x, wfrag, b1, b2, dv_p1, dv_p2, dv_s2,
                                             g1, g2s, g2p);

    // --- fused hop 1 (3 branches) + fused hop 2 (final z1, z2) ---
    spmm1_kernel<<<NB_SPMM, 256, 0, stream>>>((const uint*)g1, (const uint*)g2p, (const uint*)g2s,
                                              gt1, gtp, gts,
                                              off_p, cnt_p, csr_p, off_s, cnt_s, csr_s,
                                              dv_p1, dv_p2, dv_s2);
    spmm2_kernel<<<NB_SPMM, 256, 0, stream>>>((const uint*)gt1, (const uint*)gtp, (const uint*)gts,
                                              off_p, cnt_p, csr_p, off_s, cnt_s, csr_s,
                                              dv_p1, dv_p2, dv_s2,
                                              out, out + (size_t)NN * HH);
}